// Round 9
// baseline (172.243 us; speedup 1.0000x reference)
//
#include <hip/hip_runtime.h>
#include <hip/hip_bf16.h>

// B=4, Y=64, X=64, C=256, H=8, F=32, 7x7 window (S=49). All I/O is FLOAT32.
static constexpr int NPOS = 4 * 64 * 64;   // 16384 rows
static constexpr int CD   = 256;

typedef __attribute__((ext_vector_type(8))) short bf16x8;   // MFMA A/B frag
typedef __attribute__((ext_vector_type(4))) float f32x4;    // MFMA C/D frag

__device__ __forceinline__ float bflo(unsigned int u) { return __uint_as_float(u << 16); }
__device__ __forceinline__ float bfhi(unsigned int u) { return __uint_as_float(u & 0xffff0000u); }

__device__ __forceinline__ unsigned int packbf2(float lo, float hi) {
    union { __hip_bfloat162 h; unsigned int u; } cv;
    cv.h.x = __float2bfloat16(lo);
    cv.h.y = __float2bfloat16(hi);
    return cv.u;
}
__device__ __forceinline__ uint4 pack8(float4 a, float4 b) {
    uint4 u;
    u.x = packbf2(a.x, a.y); u.y = packbf2(a.z, a.w);
    u.z = packbf2(b.x, b.y); u.w = packbf2(b.z, b.w);
    return u;
}

// DPP cross-lane move (VALU pipe, no LDS): returns v from lane per CTRL.
template<int CTRL>
__device__ __forceinline__ float dpp_mov(float v) {
    return __int_as_float(
        __builtin_amdgcn_update_dpp(0, __float_as_int(v), CTRL, 0xF, 0xF, true));
}

// ---------------------------------------------------------------------------
// Convert: pack Wq|Wk|Wv (6 col-tiles of 128) and Wo (2 tiles) into MFMA
// b-frag order bf16. slot=(T*8+kstep)*8+ng; lane L holds
// W[k=kstep*32+(L>>4)*8+j][n=T*128+ng*16+(L&15)], j=0..7 contiguous.
// ---------------------------------------------------------------------------
__global__ __launch_bounds__(256) void convert_kernel(
    const float* __restrict__ Wq, const float* __restrict__ Wk,
    const float* __restrict__ Wv, const float* __restrict__ Wo,
    __hip_bfloat16* __restrict__ Wfrag,    // 384 KB
    __hip_bfloat16* __restrict__ Wofrag)   // 128 KB
{
    int t = blockIdx.x * 256 + threadIdx.x;
    if (t < 24576) {
        int L = t & 63, ng = (t >> 6) & 7, s = (t >> 9) & 7, T = t >> 12;
        int mat = T >> 1;
        const float* src = (mat == 0) ? Wq : (mat == 1) ? Wk : Wv;
        int ncol  = (T & 1) * 128 + ng * 16 + (L & 15);
        int kbase = s * 32 + (L >> 4) * 8;
        __hip_bfloat16* dst = Wfrag + ((size_t)((T * 8 + s) * 8 + ng) * 64 + L) * 8;
#pragma unroll
        for (int j = 0; j < 8; ++j)
            dst[j] = __float2bfloat16(src[(kbase + j) * 256 + ncol]);
    } else {
        int u = t - 24576;
        int L = u & 63, ng = (u >> 6) & 7, s = (u >> 9) & 7, T = (u >> 12) & 1;
        int ncol  = T * 128 + ng * 16 + (L & 15);
        int kbase = s * 32 + (L >> 4) * 8;
        __hip_bfloat16* dst = Wofrag + ((size_t)((T * 8 + s) * 8 + ng) * 64 + L) * 8;
#pragma unroll
        for (int j = 0; j < 8; ++j)
            dst[j] = __float2bfloat16(Wo[(kbase + j) * 256 + ncol]);
    }
}

// ---------------------------------------------------------------------------
// Kernel 1: fused QKV GEMM. grid=(256, 3): g=0->Q(+pe), 1->K, 2->V.
// Block: 64 rows x 256 cols; wave w = 64 rows x cols [w*64,+64) = 4x4 frags.
// LDS double-buffer + DEPTH-2 register prefetch: loads issued 2 K-steps
// before use so ~2 full steps of MFMA cover global-load latency.
// ---------------------------------------------------------------------------
__global__ __launch_bounds__(256, 4) void qkv_mfma(
    const float* __restrict__ x,
    const __hip_bfloat16* __restrict__ Wfrag,
    const float* __restrict__ pe,
    __hip_bfloat16* __restrict__ QA,
    __hip_bfloat16* __restrict__ Kd,
    __hip_bfloat16* __restrict__ Vd)
{
    __shared__ __align__(16) short As[2][64 * 32];   // 2 x 4 KB
    const int t = threadIdx.x;
    const int rowbase = blockIdx.x * 64;
    const int g = blockIdx.y;                      // 0=Q,1=K,2=V
    const int L = t & 63;
    const int wave = t >> 6;
    const int quad = L >> 4, lrow = L & 15;
    const int T = g * 2 + (wave >> 1);             // Wfrag 128-col tile
    const int ngb = (wave & 1) * 4;                // 16-col group base

    f32x4 acc[4][4];
#pragma unroll
    for (int i = 0; i < 4; ++i)
#pragma unroll
        for (int j = 0; j < 4; ++j) acc[i][j] = (f32x4){0.f, 0.f, 0.f, 0.f};

    const int r_st = t >> 2;
    const float* xsrc = x + (size_t)(rowbase + r_st) * CD + (t & 3) * 8;
    const int ai = r_st * 4 + (t & 3);

    // prologue: stage s=0; prefetch s=1 (p0) and s=2 (p1)
    float4 t0 = ((const float4*)xsrc)[0];
    float4 t1 = ((const float4*)xsrc)[1];
    ((uint4*)As[0])[ai] = pack8(t0, t1);
    float4 p00 = ((const float4*)(xsrc + 32))[0];
    float4 p01 = ((const float4*)(xsrc + 32))[1];
    float4 p10 = ((const float4*)(xsrc + 64))[0];
    float4 p11 = ((const float4*)(xsrc + 64))[1];
    __syncthreads();

#pragma unroll
    for (int s = 0; s < 8; ++s) {                  // K=256, BK=32
        bf16x8 bf[4];
#pragma unroll
        for (int j = 0; j < 4; ++j)
            bf[j] = *(const bf16x8*)(Wfrag +
                     ((size_t)((T * 8 + s) * 8 + ngb + j) * 64 + L) * 8);
        if (s < 7) {
            if (s & 1) {
                ((uint4*)As[(s + 1) & 1])[ai] = pack8(p10, p11);
                if (s + 3 < 8) {
                    p10 = ((const float4*)(xsrc + (s + 3) * 32))[0];
                    p11 = ((const float4*)(xsrc + (s + 3) * 32))[1];
                }
            } else {
                ((uint4*)As[(s + 1) & 1])[ai] = pack8(p00, p01);
                if (s + 3 < 8) {
                    p00 = ((const float4*)(xsrc + (s + 3) * 32))[0];
                    p01 = ((const float4*)(xsrc + (s + 3) * 32))[1];
                }
            }
        }
        const short* Ab = As[s & 1];
#pragma unroll
        for (int i = 0; i < 4; ++i) {
            bf16x8 af = *(const bf16x8*)(Ab + (i * 16 + lrow) * 32 + quad * 8);
#pragma unroll
            for (int j = 0; j < 4; ++j)
                acc[i][j] = __builtin_amdgcn_mfma_f32_16x16x32_bf16(af, bf[j], acc[i][j], 0, 0, 0);
        }
        __syncthreads();
    }

#pragma unroll
    for (int i = 0; i < 4; ++i) {
#pragma unroll
        for (int r = 0; r < 4; ++r) {
            int row = rowbase + i * 16 + quad * 4 + r;
            if (g == 0) {
                int yy = (row >> 6) & 63, xx = row & 63;
                int cy = min(max(yy, 3), 60), cx = min(max(xx, 3), 60);
                int qidx = (yy - cy + 3) * 7 + (xx - cx + 3);
#pragma unroll
                for (int j = 0; j < 4; ++j) {
                    int c = wave * 64 + j * 16 + lrow;
                    QA[(size_t)row * CD + c] =
                        __float2bfloat16(acc[i][j][r] + pe[qidx * 256 + c]);
                }
            } else {
                __hip_bfloat16* O = (g == 1) ? Kd : Vd;
#pragma unroll
                for (int j = 0; j < 4; ++j) {
                    int c = wave * 64 + j * 16 + lrow;
                    O[(size_t)row * CD + c] = __float2bfloat16(acc[i][j][r]);
                }
            }
        }
    }
}

// ---------------------------------------------------------------------------
// Kernel 2: local attention. 512 thr = 8 waves = 8 consecutive positions
// (wave = 1 position, coalesced uint2 K/V). VALU diet (no-max softmax,
// Q.pe distribution, DPP butterfly, exp2) + pe staged ONCE per block into
// LDS as bf16 (25 KB): pe bytes halve and move off the L1 pipe, which r8
// showed carries ~50% of attn's traffic (K 25KB + V 25KB + pe-f32 50KB/wave).
// ---------------------------------------------------------------------------
__global__ __launch_bounds__(512) void attn_kernel(
    unsigned int* QA,                         // bf16 [NPOS][256] as uint[..][128]
    const unsigned int* __restrict__ Kd,
    const unsigned int* __restrict__ Vd,
    const float* __restrict__ pe)             // f32 [49][256]
{
    __shared__ unsigned int pes[49 * 128];    // bf16x2, 25 KB
    const int t = threadIdx.x;
    for (int idx = t; idx < 49 * 128; idx += 512) {
        float2 p = ((const float2*)pe)[idx];
        pes[idx] = packbf2(p.x, p.y);
    }
    __syncthreads();

    const int lane = t & 63;
    const int pos = blockIdx.x * 8 + (t >> 6);
    const int xx = pos & 63;
    const int yy = (pos >> 6) & 63;
    const int bb = pos >> 12;
    const int cy = min(max(yy, 3), 60);
    const int cx = min(max(xx, 3), 60);
    const int c2 = lane * 2;                  // packed-uint channel index

    unsigned int* qp = QA + (size_t)pos * 128 + c2;
    const uint2 q = *(const uint2*)qp;
    // fold softmax scale AND log2(e) into Q: p = exp2(qs * Q.(K+pe))
    const float qs = 0.17677669529663687f * 1.4426950408889634f;
    const float qx = bflo(q.x) * qs, qy = bfhi(q.x) * qs;
    const float qz = bflo(q.y) * qs, qw = bfhi(q.y) * qs;

    float l = 0.f;
    float a0 = 0.f, a1 = 0.f, a2 = 0.f, a3 = 0.f;
    const int center = (bb << 12) + (cy << 6) + cx;

    for (int sy = 0; sy < 7; ++sy) {
        const int np0 = center + ((sy - 3) << 6) - 3;
        float b[7];
#pragma unroll
        for (int sx = 0; sx < 7; ++sx) {      // per-lane partial of Q.pe[s], LDS
            const uint2 pv = *(const uint2*)(pes + (sy * 7 + sx) * 128 + c2);
            b[sx] = fmaf(qx, bflo(pv.x),
                    fmaf(qy, bfhi(pv.x),
                    fmaf(qz, bflo(pv.y), qw * bfhi(pv.y))));
        }
#pragma unroll
        for (int sx = 0; sx < 7; ++sx) {
            const int np = np0 + sx;
            const uint2 kk = *(const uint2*)(Kd + (size_t)np * 128 + c2);
            float d = fmaf(qx, bflo(kk.x),
                      fmaf(qy, bfhi(kk.x),
                      fmaf(qz, bflo(kk.y),
                      fmaf(qw, bfhi(kk.y), b[sx]))));
            d += dpp_mov<0xB1>(d);            // + lane^1   (quad_perm, VALU)
            d += dpp_mov<0x4E>(d);            // + lane^2   (quad_perm, VALU)
            d += dpp_mov<0x141>(d);           // + other quad (row_half_mirror)
            const float p = exp2f(d);         // no-max softmax (bounded scores)
            l += p;
            const uint2 vv = *(const uint2*)(Vd + (size_t)np * 128 + c2);
            a0 = fmaf(p, bflo(vv.x), a0);
            a1 = fmaf(p, bfhi(vv.x), a1);
            a2 = fmaf(p, bflo(vv.y), a2);
            a3 = fmaf(p, bfhi(vv.y), a3);
        }
    }
    const float inv = 1.f / (l + 1e-8f);
    qp[0] = packbf2(a0 * inv, a1 * inv);
    qp[1] = packbf2(a2 * inv, a3 * inv);
}

// ---------------------------------------------------------------------------
// Kernel 3: output projection A(bf16) @ Wo -> out f32. grid=256, 64-row
// tiles; LDS dbuf + depth-2 prefetch like qkv. Overwrites d_out.
// ---------------------------------------------------------------------------
__global__ __launch_bounds__(256, 4) void oproj_mfma(
    const unsigned int* __restrict__ A,       // QA as uint [NPOS][128]
    const __hip_bfloat16* __restrict__ Wofrag,
    float* __restrict__ out)
{
    __shared__ __align__(16) short As[2][64 * 32];
    const int t = threadIdx.x;
    const int rowbase = blockIdx.x * 64;
    const int L = t & 63;
    const int wave = t >> 6;
    const int quad = L >> 4, lrow = L & 15;
    const int T = wave >> 1;
    const int ngb = (wave & 1) * 4;

    f32x4 acc[4][4];
#pragma unroll
    for (int i = 0; i < 4; ++i)
#pragma unroll
        for (int j = 0; j < 4; ++j) acc[i][j] = (f32x4){0.f, 0.f, 0.f, 0.f};

    const int r_st = t >> 2;
    const uint4* asrc = (const uint4*)A + (size_t)(rowbase + r_st) * 32 + (t & 3);
    const int ai = r_st * 4 + (t & 3);

    ((uint4*)As[0])[ai] = asrc[0];
    uint4 pf0 = asrc[4];                           // s=1
    uint4 pf1 = asrc[8];                           // s=2
    __syncthreads();

#pragma unroll
    for (int s = 0; s < 8; ++s) {
        bf16x8 bf[4];
#pragma unroll
        for (int j = 0; j < 4; ++j)
            bf[j] = *(const bf16x8*)(Wofrag +
                     ((size_t)((T * 8 + s) * 8 + ngb + j) * 64 + L) * 8);
        if (s < 7) {
            if (s & 1) {
                ((uint4*)As[(s + 1) & 1])[ai] = pf1;
                if (s + 3 < 8) pf1 = asrc[(s + 3) * 4];
            } else {
                ((uint4*)As[(s + 1) & 1])[ai] = pf0;
                if (s + 3 < 8) pf0 = asrc[(s + 3) * 4];
            }
        }
        const short* Ab = As[s & 1];
#pragma unroll
        for (int i = 0; i < 4; ++i) {
            bf16x8 af = *(const bf16x8*)(Ab + (i * 16 + lrow) * 32 + quad * 8);
#pragma unroll
            for (int j = 0; j < 4; ++j)
                acc[i][j] = __builtin_amdgcn_mfma_f32_16x16x32_bf16(af, bf[j], acc[i][j], 0, 0, 0);
        }
        __syncthreads();
    }

#pragma unroll
    for (int i = 0; i < 4; ++i)
#pragma unroll
        for (int r = 0; r < 4; ++r) {
            int row = rowbase + i * 16 + quad * 4 + r;
#pragma unroll
            for (int j = 0; j < 4; ++j) {
                int c = wave * 64 + j * 16 + lrow;
                out[(size_t)row * CD + c] = acc[i][j][r];
            }
        }
}

// ---------------------------------------------------------------------------
// Memory plan:
//   ws[0, 8MB):            QA bf16 (Q w/ pos_emb -> in-place attn output A)
//   ws[8MB, +384KB):       Wfrag (QKV b-frag order)     total 8.5 MB
//   ws[+384KB, +128KB):    Wofrag
//   d_out[0,8MB)/[8,16MB): K / V bf16 scratch; oproj overwrites with f32 out
// ---------------------------------------------------------------------------
extern "C" void kernel_launch(void* const* d_in, const int* in_sizes, int n_in,
                              void* d_out, int out_size, void* d_ws, size_t ws_size,
                              hipStream_t stream)
{
    const float* x  = (const float*)d_in[0];
    const float* Wq = (const float*)d_in[1];
    const float* Wk = (const float*)d_in[2];
    const float* Wv = (const float*)d_in[3];
    const float* Wo = (const float*)d_in[4];
    const float* pe = (const float*)d_in[5];
    float* out = (float*)d_out;

    char* ws = (char*)d_ws;
    __hip_bfloat16* QA     = (__hip_bfloat16*)ws;
    __hip_bfloat16* Wfrag  = (__hip_bfloat16*)(ws + (8u << 20));
    __hip_bfloat16* Wofrag = (__hip_bfloat16*)(ws + (8u << 20) + (384u << 10));
    __hip_bfloat16* Kd = (__hip_bfloat16*)d_out;
    __hip_bfloat16* Vd = (__hip_bfloat16*)((char*)d_out + (8u << 20));

    convert_kernel<<<128, 256, 0, stream>>>(Wq, Wk, Wv, Wo, Wfrag, Wofrag);
    qkv_mfma<<<dim3(256, 3), 256, 0, stream>>>(x, Wfrag, pe, QA, Kd, Vd);
    attn_kernel<<<2048, 512, 0, stream>>>((unsigned int*)QA,
                                          (const unsigned int*)Kd,
                                          (const unsigned int*)Vd, pe);
    oproj_mfma<<<256, 256, 0, stream>>>((const unsigned int*)QA, Wofrag, out);
}

// Round 10
// 139.393 us; speedup vs baseline: 1.2357x; 1.2357x over previous
//
#include <hip/hip_runtime.h>
#include <hip/hip_bf16.h>

// B=4, Y=64, X=64, C=256, H=8, F=32, 7x7 window (S=49). All I/O is FLOAT32.
static constexpr int NPOS = 4 * 64 * 64;   // 16384 rows
static constexpr int CD   = 256;
// softmax scale (1/sqrt(32)) * log2(e), folded into K and pe_k at pack time
#define QSCALE (0.17677669529663687f * 1.4426950408889634f)

typedef __attribute__((ext_vector_type(8))) short bf16x8;   // MFMA A/B frag
typedef __attribute__((ext_vector_type(4))) float f32x4;    // MFMA C/D frag

__device__ __forceinline__ float bflo(unsigned int u) { return __uint_as_float(u << 16); }
__device__ __forceinline__ float bfhi(unsigned int u) { return __uint_as_float(u & 0xffff0000u); }

__device__ __forceinline__ unsigned short bfbits(float f) {
    union { __hip_bfloat16 h; unsigned short u; } cv;
    cv.h = __float2bfloat16(f);
    return cv.u;
}
__device__ __forceinline__ unsigned int packbf2(float lo, float hi) {
    union { __hip_bfloat162 h; unsigned int u; } cv;
    cv.h.x = __float2bfloat16(lo);
    cv.h.y = __float2bfloat16(hi);
    return cv.u;
}
__device__ __forceinline__ uint4 pack8(float4 a, float4 b) {
    uint4 u;
    u.x = packbf2(a.x, a.y); u.y = packbf2(a.z, a.w);
    u.z = packbf2(b.x, b.y); u.w = packbf2(b.z, b.w);
    return u;
}
template<int CTRL>
__device__ __forceinline__ float dpp_mov(float v) {
    return __int_as_float(
        __builtin_amdgcn_update_dpp(0, __float_as_int(v), CTRL, 0xF, 0xF, true));
}
template<int IMM>
__device__ __forceinline__ float swz(float v) {
    return __int_as_float(__builtin_amdgcn_ds_swizzle(__float_as_int(v), IMM));
}

// ---------------------------------------------------------------------------
// convert1: Wfrag (Wq|Wk|Wv b-frag order bf16, 384 KB, into d_out) and pebf
// (pe^T b-frag order, scaled by QSCALE, 32 KB, into d_out).
// pebf[(h*4+Tn)*64 + L][j] = pe[s][h*32 + (L>>4)*8 + j]*QSCALE, s=Tn*16+(L&15).
// ---------------------------------------------------------------------------
__global__ __launch_bounds__(256) void convert1_kernel(
    const float* __restrict__ Wq, const float* __restrict__ Wk,
    const float* __restrict__ Wv, const float* __restrict__ pe,
    __hip_bfloat16* __restrict__ Wfrag,
    __hip_bfloat16* __restrict__ pebf)
{
    int t = blockIdx.x * 256 + threadIdx.x;
    if (t < 24576) {
        int L = t & 63, ng = (t >> 6) & 7, s = (t >> 9) & 7, T = t >> 12;
        int mat = T >> 1;
        const float* src = (mat == 0) ? Wq : (mat == 1) ? Wk : Wv;
        int ncol  = (T & 1) * 128 + ng * 16 + (L & 15);
        int kbase = s * 32 + (L >> 4) * 8;
        __hip_bfloat16* dst = Wfrag + ((size_t)((T * 8 + s) * 8 + ng) * 64 + L) * 8;
#pragma unroll
        for (int j = 0; j < 8; ++j)
            dst[j] = __float2bfloat16(src[(kbase + j) * 256 + ncol]);
    } else if (t < 24576 + 2048) {
        int u = t - 24576;
        int L = u & 63, Tn = (u >> 6) & 3, h = u >> 8;
        int s = Tn * 16 + (L & 15);
        int kbase = (L >> 4) * 8;
        __hip_bfloat16* dst = pebf + ((size_t)((h * 4 + Tn) * 64 + L)) * 8;
#pragma unroll
        for (int j = 0; j < 8; ++j) {
            float v = (s < 49) ? pe[s * 256 + h * 32 + kbase + j] * QSCALE : 0.f;
            dst[j] = __float2bfloat16(v);
        }
    }
}

// ---------------------------------------------------------------------------
// convert2: Wofrag (b-frag order) into ws+8MB (Kd region, dead after attn).
// Runs AFTER attn so oproj's d_out writes can't race frag reads.
// ---------------------------------------------------------------------------
__global__ __launch_bounds__(256) void convert2_kernel(
    const float* __restrict__ Wo,
    __hip_bfloat16* __restrict__ Wofrag)
{
    int u = blockIdx.x * 256 + threadIdx.x;   // 8192 threads
    int L = u & 63, ng = (u >> 6) & 7, s = (u >> 9) & 7, T = (u >> 12) & 1;
    int ncol  = T * 128 + ng * 16 + (L & 15);
    int kbase = s * 32 + (L >> 4) * 8;
    __hip_bfloat16* dst = Wofrag + ((size_t)((T * 8 + s) * 8 + ng) * 64 + L) * 8;
#pragma unroll
    for (int j = 0; j < 8; ++j)
        dst[j] = __float2bfloat16(Wo[(kbase + j) * 256 + ncol]);
}

// ---------------------------------------------------------------------------
// Kernel 1: fused QKV GEMM. grid=(256, 3): g=0->Q(+pe_q)->QA, 1->K (scaled by
// QSCALE) -> Kd (ws), 2 -> V TRANSPOSED -> Vt[ch][pos+3] (d_out).
// 64-row tiles, LDS dbuf + depth-2 register prefetch (r9 structure).
// ---------------------------------------------------------------------------
__global__ __launch_bounds__(256, 4) void qkv_mfma(
    const float* __restrict__ x,
    const __hip_bfloat16* __restrict__ Wfrag,
    const float* __restrict__ pe,
    unsigned short* __restrict__ QA,
    unsigned short* __restrict__ Kd,
    unsigned short* __restrict__ Vt)
{
    __shared__ __align__(16) short As[2][64 * 32];
    const int t = threadIdx.x;
    const int rowbase = blockIdx.x * 64;
    const int g = blockIdx.y;
    const int L = t & 63;
    const int wave = t >> 6;
    const int quad = L >> 4, lrow = L & 15;
    const int T = g * 2 + (wave >> 1);
    const int ngb = (wave & 1) * 4;

    f32x4 acc[4][4];
#pragma unroll
    for (int i = 0; i < 4; ++i)
#pragma unroll
        for (int j = 0; j < 4; ++j) acc[i][j] = (f32x4){0.f, 0.f, 0.f, 0.f};

    const int r_st = t >> 2;
    const float* xsrc = x + (size_t)(rowbase + r_st) * CD + (t & 3) * 8;
    const int ai = r_st * 4 + (t & 3);

    float4 t0 = ((const float4*)xsrc)[0];
    float4 t1 = ((const float4*)xsrc)[1];
    ((uint4*)As[0])[ai] = pack8(t0, t1);
    float4 p00 = ((const float4*)(xsrc + 32))[0];
    float4 p01 = ((const float4*)(xsrc + 32))[1];
    float4 p10 = ((const float4*)(xsrc + 64))[0];
    float4 p11 = ((const float4*)(xsrc + 64))[1];
    __syncthreads();

#pragma unroll
    for (int s = 0; s < 8; ++s) {
        bf16x8 bf[4];
#pragma unroll
        for (int j = 0; j < 4; ++j)
            bf[j] = *(const bf16x8*)(Wfrag +
                     ((size_t)((T * 8 + s) * 8 + ngb + j) * 64 + L) * 8);
        if (s < 7) {
            if (s & 1) {
                ((uint4*)As[(s + 1) & 1])[ai] = pack8(p10, p11);
                if (s + 3 < 8) {
                    p10 = ((const float4*)(xsrc + (s + 3) * 32))[0];
                    p11 = ((const float4*)(xsrc + (s + 3) * 32))[1];
                }
            } else {
                ((uint4*)As[(s + 1) & 1])[ai] = pack8(p00, p01);
                if (s + 3 < 8) {
                    p00 = ((const float4*)(xsrc + (s + 3) * 32))[0];
                    p01 = ((const float4*)(xsrc + (s + 3) * 32))[1];
                }
            }
        }
        const short* Ab = As[s & 1];
#pragma unroll
        for (int i = 0; i < 4; ++i) {
            bf16x8 af = *(const bf16x8*)(Ab + (i * 16 + lrow) * 32 + quad * 8);
#pragma unroll
            for (int j = 0; j < 4; ++j)
                acc[i][j] = __builtin_amdgcn_mfma_f32_16x16x32_bf16(af, bf[j], acc[i][j], 0, 0, 0);
        }
        __syncthreads();
    }

#pragma unroll
    for (int i = 0; i < 4; ++i) {
#pragma unroll
        for (int r = 0; r < 4; ++r) {
            int row = rowbase + i * 16 + quad * 4 + r;
            if (g == 0) {
                int yy = (row >> 6) & 63, xx = row & 63;
                int cy = min(max(yy, 3), 60), cx = min(max(xx, 3), 60);
                int qidx = (yy - cy + 3) * 7 + (xx - cx + 3);
#pragma unroll
                for (int j = 0; j < 4; ++j) {
                    int c = wave * 64 + j * 16 + lrow;
                    QA[(size_t)row * CD + c] = bfbits(acc[i][j][r] + pe[qidx * 256 + c]);
                }
            } else if (g == 1) {
#pragma unroll
                for (int j = 0; j < 4; ++j) {
                    int c = wave * 64 + j * 16 + lrow;
                    Kd[(size_t)row * CD + c] = bfbits(acc[i][j][r] * QSCALE);
                }
            } else {
#pragma unroll
                for (int j = 0; j < 4; ++j) {
                    int c = wave * 64 + j * 16 + lrow;
                    Vt[(size_t)c * 16384 + row + 3] = bfbits(acc[i][j][r]);
                }
            }
        }
    }
}

// ---------------------------------------------------------------------------
// Kernel 2: MFMA local attention. Unit = (16-position x-run, 1 head), one
// wave per unit, 4 units/block (no __syncthreads; LDS buffers per-wave).
// Per dy (7 window rows): Sc = banded QK^T (2 MFMAs over a 32-col K patch,
// per-lane clamped cols), P = exp2(Sc + Qpe[i][s]) masked to the 7-slot band
// (no-max softmax; QSCALE*log2e pre-folded into Kd/pebf), P->LDS->A-frag,
// O += P @ Vt (2 MFMAs, coalesced 16B/lane loads from transposed V).
// Qpe[i][s] = Q.pe_k (49 slots) via 4 MFMAs once per unit. l via MFMA-free
// per-quad 16-lane reduce at the end (plain sums - no-max softmax).
// ---------------------------------------------------------------------------
__global__ __launch_bounds__(256) void attn_mfma(
    unsigned short* QA,                      // bf16 [pos][256]; Q in, A out
    const unsigned short* __restrict__ Kd,   // bf16 [pos][256], pre-scaled
    const unsigned short* __restrict__ Vt,   // bf16 [ch][16384], +3 shift
    const __hip_bfloat16* __restrict__ pebf) // [h*4+Tn][64][8], pre-scaled
{
    __shared__ float qpes[4][16 * 64];                    // per-wave Qpe
    __shared__ __align__(16) unsigned short ps[4][16 * 40]; // per-wave P
    const int t = threadIdx.x, w = t >> 6, L = t & 63;
    const int lrow = L & 15, quad = L >> 4;
    const int id = blockIdx.x * 4 + w;        // unit in [0, 8192)
    const int tile = id >> 3, h = id & 7;
    const int pos0 = tile * 16;
    const int x0 = pos0 & 63;
    const int yy = (pos0 >> 6) & 63, bb = pos0 >> 12;
    const int cy = min(max(yy, 3), 60);

    // per-lane row indices i = quad*4+r; band center offset cxr = clip(x)-x0
    int cxr[4];
#pragma unroll
    for (int r = 0; r < 4; ++r)
        cxr[r] = min(max(x0 + quad * 4 + r, 3), 60) - x0;

    // clamped K patch columns for the two N-tiles (patch base = x0-3)
    const int kc0 = min(max(x0 - 3 + lrow, 0), 63);
    const int kc1 = min(max(x0 + 13 + lrow, 0), 63);

    // Q A-frag (reused for Qpe GEMM and all QK^T MFMAs)
    const bf16x8 qa = *(const bf16x8*)(QA + (size_t)(pos0 + lrow) * 256 + h * 32 + quad * 8);

    // Qpe[i][s] via 4 MFMAs -> LDS
    float* qp = qpes[w];
    const f32x4 zero = {0.f, 0.f, 0.f, 0.f};
#pragma unroll
    for (int Tn = 0; Tn < 4; ++Tn) {
        bf16x8 bp = *(const bf16x8*)(pebf + ((size_t)((h * 4 + Tn) * 64 + L)) * 8);
        f32x4 c = __builtin_amdgcn_mfma_f32_16x16x32_bf16(qa, bp, zero, 0, 0, 0);
#pragma unroll
        for (int r = 0; r < 4; ++r)
            qp[(quad * 4 + r) * 64 + Tn * 16 + lrow] = c[r];
    }
    __builtin_amdgcn_s_waitcnt(0xc07f);       // drain LDS writes (cross-lane)

    float lacc[4] = {0.f, 0.f, 0.f, 0.f};
    f32x4 o0 = zero, o1 = zero;
    unsigned short* pw = ps[w];
    int rowpos = bb * 4096 + (cy - 3) * 64;

    for (int dy = 0; dy < 7; ++dy, rowpos += 64) {
        const bf16x8 bk0 = *(const bf16x8*)(Kd + (size_t)(rowpos + kc0) * 256 + h * 32 + quad * 8);
        const bf16x8 bk1 = *(const bf16x8*)(Kd + (size_t)(rowpos + kc1) * 256 + h * 32 + quad * 8);
        f32x4 sc0 = __builtin_amdgcn_mfma_f32_16x16x32_bf16(qa, bk0, zero, 0, 0, 0);
        f32x4 sc1 = __builtin_amdgcn_mfma_f32_16x16x32_bf16(qa, bk1, zero, 0, 0, 0);
        const int dy7 = dy * 7;
#pragma unroll
        for (int r = 0; r < 4; ++r) {
            const int i = quad * 4 + r;
            {
                int dx3 = lrow - cxr[r];                       // n - center
                float qpe = qp[i * 64 + dy7 + min(max(dx3, 0), 6)];
                float e = exp2f(sc0[r] + qpe);
                float p = ((unsigned)dx3 <= 6u) ? e : 0.f;
                lacc[r] += p;
                pw[i * 40 + lrow] = bfbits(p);
            }
            {
                int dx3 = 16 + lrow - cxr[r];
                float qpe = qp[i * 64 + dy7 + min(max(dx3, 0), 6)];
                float e = exp2f(sc1[r] + qpe);
                float p = ((unsigned)dx3 <= 6u) ? e : 0.f;
                lacc[r] += p;
                pw[i * 40 + 16 + lrow] = bfbits(p);
            }
        }
        __builtin_amdgcn_s_waitcnt(0xc07f);    // P writes visible to A-frag read
        const bf16x8 pa = *(const bf16x8*)(pw + lrow * 40 + quad * 8);
        const bf16x8 bv0 = *(const bf16x8*)(Vt + (size_t)(h * 32 + lrow) * 16384 + rowpos + x0 + quad * 8);
        const bf16x8 bv1 = *(const bf16x8*)(Vt + (size_t)(h * 32 + 16 + lrow) * 16384 + rowpos + x0 + quad * 8);
        o0 = __builtin_amdgcn_mfma_f32_16x16x32_bf16(pa, bv0, o0, 0, 0, 0);
        o1 = __builtin_amdgcn_mfma_f32_16x16x32_bf16(pa, bv1, o1, 0, 0, 0);
    }

    // l[i]: reduce lacc across the 16 lanes of this quad (xor 1,2,4,8)
#pragma unroll
    for (int r = 0; r < 4; ++r) {
        float v = lacc[r];
        v += dpp_mov<0xB1>(v);       // xor 1
        v += dpp_mov<0x4E>(v);       // xor 2
        v += swz<0x101F>(v);         // xor 4
        v += swz<0x201F>(v);         // xor 8
        const float inv = 1.f / (v + 1e-8f);
        const int row = pos0 + quad * 4 + r;
        QA[(size_t)row * 256 + h * 32 + lrow]      = bfbits(o0[r] * inv);
        QA[(size_t)row * 256 + h * 32 + 16 + lrow] = bfbits(o1[r] * inv);
    }
}

// ---------------------------------------------------------------------------
// Kernel 3: output projection A(bf16) @ Wo -> out f32. grid=256, 64-row
// tiles; LDS dbuf + depth-2 prefetch. Overwrites d_out (Vt/frags dead).
// ---------------------------------------------------------------------------
__global__ __launch_bounds__(256, 4) void oproj_mfma(
    const unsigned int* __restrict__ A,       // QA as uint [NPOS][128]
    const __hip_bfloat16* __restrict__ Wofrag,
    float* __restrict__ out)
{
    __shared__ __align__(16) short As[2][64 * 32];
    const int t = threadIdx.x;
    const int rowbase = blockIdx.x * 64;
    const int L = t & 63;
    const int wave = t >> 6;
    const int quad = L >> 4, lrow = L & 15;
    const int T = wave >> 1;
    const int ngb = (wave & 1) * 4;

    f32x4 acc[4][4];
#pragma unroll
    for (int i = 0; i < 4; ++i)
#pragma unroll
        for (int j = 0; j < 4; ++j) acc[i][j] = (f32x4){0.f, 0.f, 0.f, 0.f};

    const int r_st = t >> 2;
    const uint4* asrc = (const uint4*)A + (size_t)(rowbase + r_st) * 32 + (t & 3);
    const int ai = r_st * 4 + (t & 3);

    ((uint4*)As[0])[ai] = asrc[0];
    uint4 pf0 = asrc[4];
    uint4 pf1 = asrc[8];
    __syncthreads();

#pragma unroll
    for (int s = 0; s < 8; ++s) {
        bf16x8 bf[4];
#pragma unroll
        for (int j = 0; j < 4; ++j)
            bf[j] = *(const bf16x8*)(Wofrag +
                     ((size_t)((T * 8 + s) * 8 + ngb + j) * 64 + L) * 8);
        if (s < 7) {
            if (s & 1) {
                ((uint4*)As[(s + 1) & 1])[ai] = pf1;
                if (s + 3 < 8) pf1 = asrc[(s + 3) * 4];
            } else {
                ((uint4*)As[(s + 1) & 1])[ai] = pf0;
                if (s + 3 < 8) pf0 = asrc[(s + 3) * 4];
            }
        }
        const short* Ab = As[s & 1];
#pragma unroll
        for (int i = 0; i < 4; ++i) {
            bf16x8 af = *(const bf16x8*)(Ab + (i * 16 + lrow) * 32 + quad * 8);
#pragma unroll
            for (int j = 0; j < 4; ++j)
                acc[i][j] = __builtin_amdgcn_mfma_f32_16x16x32_bf16(af, bf[j], acc[i][j], 0, 0, 0);
        }
        __syncthreads();
    }

#pragma unroll
    for (int i = 0; i < 4; ++i)
#pragma unroll
        for (int r = 0; r < 4; ++r) {
            int row = rowbase + i * 16 + quad * 4 + r;
#pragma unroll
            for (int j = 0; j < 4; ++j) {
                int c = wave * 64 + j * 16 + lrow;
                out[(size_t)row * CD + c] = acc[i][j][r];
            }
        }
}

// ---------------------------------------------------------------------------
// Memory plan:
//   ws[0, 8MB):      QA bf16 (Q+pe_q -> in-place attn output A)
//   ws[8, 16MB):     Kd bf16 (QSCALE-folded); dead after attn, then reused
//                    by convert2 as Wofrag (128 KB)               [ws=16MB]
//   d_out[0, ~8MB):  Vt bf16 transposed [ch][16384] (+3 shift, injective)
//   d_out[8MB+4KB, +416KB): Wfrag 384KB + pebf 32KB
//   oproj overwrites all of d_out with the final f32 output.
// ---------------------------------------------------------------------------
extern "C" void kernel_launch(void* const* d_in, const int* in_sizes, int n_in,
                              void* d_out, int out_size, void* d_ws, size_t ws_size,
                              hipStream_t stream)
{
    const float* x  = (const float*)d_in[0];
    const float* Wq = (const float*)d_in[1];
    const float* Wk = (const float*)d_in[2];
    const float* Wv = (const float*)d_in[3];
    const float* Wo = (const float*)d_in[4];
    const float* pe = (const float*)d_in[5];
    float* out = (float*)d_out;

    char* ws  = (char*)d_ws;
    char* dob = (char*)d_out;
    unsigned short* QA = (unsigned short*)ws;                    // 8 MB
    unsigned short* Kd = (unsigned short*)(ws + (8u << 20));     // 8 MB
    __hip_bfloat16* Wofrag = (__hip_bfloat16*)(ws + (8u << 20)); // aliases Kd (after attn)
    unsigned short* Vt = (unsigned short*)dob;                   // ~8 MB
    __hip_bfloat16* Wfrag = (__hip_bfloat16*)(dob + (8u << 20) + 4096);
    __hip_bfloat16* pebf  = (__hip_bfloat16*)(dob + (8u << 20) + 4096 + (384u << 10));

    convert1_kernel<<<104, 256, 0, stream>>>(Wq, Wk, Wv, pe, Wfrag, pebf);
    qkv_mfma<<<dim3(256, 3), 256, 0, stream>>>(x, Wfrag, pe, QA, Kd, Vt);
    attn_mfma<<<2048, 256, 0, stream>>>(QA, Kd, Vt, pebf);
    convert2_kernel<<<32, 256, 0, stream>>>(Wo, Wofrag);
    oproj_mfma<<<256, 256, 0, stream>>>((const unsigned int*)QA, Wofrag, out);
}

// Round 11
// 138.443 us; speedup vs baseline: 1.2441x; 1.0069x over previous
//
#include <hip/hip_runtime.h>
#include <hip/hip_bf16.h>

// B=4, Y=64, X=64, C=256, H=8, F=32, 7x7 window (S=49). All I/O is FLOAT32.
static constexpr int NPOS = 4 * 64 * 64;   // 16384 rows
static constexpr int CD   = 256;
// softmax scale (1/sqrt(32)) * log2(e), folded into K and pe_k at pack time
#define QSCALE (0.17677669529663687f * 1.4426950408889634f)

typedef __attribute__((ext_vector_type(8))) short bf16x8;   // MFMA A/B frag
typedef __attribute__((ext_vector_type(4))) float f32x4;    // MFMA C/D frag

__device__ __forceinline__ float bflo(unsigned int u) { return __uint_as_float(u << 16); }
__device__ __forceinline__ float bfhi(unsigned int u) { return __uint_as_float(u & 0xffff0000u); }

__device__ __forceinline__ unsigned short bfbits(float f) {
    union { __hip_bfloat16 h; unsigned short u; } cv;
    cv.h = __float2bfloat16(f);
    return cv.u;
}
__device__ __forceinline__ unsigned int packbf2(float lo, float hi) {
    union { __hip_bfloat162 h; unsigned int u; } cv;
    cv.h.x = __float2bfloat16(lo);
    cv.h.y = __float2bfloat16(hi);
    return cv.u;
}
__device__ __forceinline__ uint4 pack8(float4 a, float4 b) {
    uint4 u;
    u.x = packbf2(a.x, a.y); u.y = packbf2(a.z, a.w);
    u.z = packbf2(b.x, b.y); u.w = packbf2(b.z, b.w);
    return u;
}
template<int CTRL>
__device__ __forceinline__ float dpp_mov(float v) {
    return __int_as_float(
        __builtin_amdgcn_update_dpp(0, __float_as_int(v), CTRL, 0xF, 0xF, true));
}
template<int IMM>
__device__ __forceinline__ float swz(float v) {
    return __int_as_float(__builtin_amdgcn_ds_swizzle(__float_as_int(v), IMM));
}
// async global->LDS copy, 16 B per lane (global_load_lds_dwordx4).
// LDS dest is wave-uniform base + lane*16 (our staging layout is exactly
// lane-contiguous, dst = &As[buf][t*8]).
__device__ __forceinline__ void async16(void* lds, const void* g) {
    __builtin_amdgcn_global_load_lds(
        (const __attribute__((address_space(1))) unsigned int*)g,
        (__attribute__((address_space(3))) unsigned int*)lds, 16, 0, 0);
}

// ---------------------------------------------------------------------------
// convert_x: x f32 -> xb bf16 (8 MB). 2048 blocks x 256, 8 elems/thread.
// ---------------------------------------------------------------------------
__global__ __launch_bounds__(256) void convertx_kernel(
    const float* __restrict__ x, unsigned short* __restrict__ xb)
{
    int t = blockIdx.x * 256 + threadIdx.x;
    const float4* s = (const float4*)x + (size_t)t * 2;
    float4 a = s[0], b = s[1];
    ((uint4*)xb)[t] = pack8(a, b);
}

// ---------------------------------------------------------------------------
// convert1: Wfrag (Wq|Wk|Wv b-frag bf16, 384 KB) + pebf (pe^T b-frag,
// QSCALE-folded, 32 KB) + Wofrag (128 KB). 136 blocks x 256.
// ---------------------------------------------------------------------------
__global__ __launch_bounds__(256) void convert1_kernel(
    const float* __restrict__ Wq, const float* __restrict__ Wk,
    const float* __restrict__ Wv, const float* __restrict__ Wo,
    const float* __restrict__ pe,
    __hip_bfloat16* __restrict__ Wfrag,
    __hip_bfloat16* __restrict__ pebf,
    __hip_bfloat16* __restrict__ Wofrag)
{
    int t = blockIdx.x * 256 + threadIdx.x;
    if (t < 24576) {
        int L = t & 63, ng = (t >> 6) & 7, s = (t >> 9) & 7, T = t >> 12;
        int mat = T >> 1;
        const float* src = (mat == 0) ? Wq : (mat == 1) ? Wk : Wv;
        int ncol  = (T & 1) * 128 + ng * 16 + (L & 15);
        int kbase = s * 32 + (L >> 4) * 8;
        __hip_bfloat16* dst = Wfrag + ((size_t)((T * 8 + s) * 8 + ng) * 64 + L) * 8;
#pragma unroll
        for (int j = 0; j < 8; ++j)
            dst[j] = __float2bfloat16(src[(kbase + j) * 256 + ncol]);
    } else if (t < 26624) {
        int u = t - 24576;
        int L = u & 63, Tn = (u >> 6) & 3, h = u >> 8;
        int s = Tn * 16 + (L & 15);
        int kbase = (L >> 4) * 8;
        __hip_bfloat16* dst = pebf + ((size_t)((h * 4 + Tn) * 64 + L)) * 8;
#pragma unroll
        for (int j = 0; j < 8; ++j) {
            float v = (s < 49) ? pe[s * 256 + h * 32 + kbase + j] * QSCALE : 0.f;
            dst[j] = __float2bfloat16(v);
        }
    } else if (t < 34816) {
        int u = t - 26624;
        int L = u & 63, ng = (u >> 6) & 7, s = (u >> 9) & 7, T = (u >> 12) & 1;
        int ncol  = T * 128 + ng * 16 + (L & 15);
        int kbase = s * 32 + (L >> 4) * 8;
        __hip_bfloat16* dst = Wofrag + ((size_t)((T * 8 + s) * 8 + ng) * 64 + L) * 8;
#pragma unroll
        for (int j = 0; j < 8; ++j)
            dst[j] = __float2bfloat16(Wo[(kbase + j) * 256 + ncol]);
    }
}

// ---------------------------------------------------------------------------
// Kernel 1: fused QKV GEMM from xb (bf16). grid=(256, 3): g=0->Q(+pe_q)->QA,
// 1->K*QSCALE->Kd, 2->V transposed->Vt[ch][pos+3].
// Staging via async global_load_lds (16B/lane) into a double-buffered LDS
// tile: prefetch for s+1 issued BEFORE the MFMA phase of s; the end-of-step
// barrier drains it after it has flown across the whole MFMA phase.
// ---------------------------------------------------------------------------
__global__ __launch_bounds__(256, 4) void qkv_mfma(
    const unsigned short* __restrict__ xb,
    const __hip_bfloat16* __restrict__ Wfrag,
    const float* __restrict__ pe,
    unsigned short* __restrict__ QA,
    unsigned short* __restrict__ Kd,
    unsigned short* __restrict__ Vt)
{
    __shared__ __align__(16) short As[2][64 * 32];
    const int t = threadIdx.x;
    const int rowbase = blockIdx.x * 64;
    const int g = blockIdx.y;
    const int L = t & 63;
    const int wave = t >> 6;
    const int quad = L >> 4, lrow = L & 15;
    const int T = g * 2 + (wave >> 1);
    const int ngb = (wave & 1) * 4;

    f32x4 acc[4][4];
#pragma unroll
    for (int i = 0; i < 4; ++i)
#pragma unroll
        for (int j = 0; j < 4; ++j) acc[i][j] = (f32x4){0.f, 0.f, 0.f, 0.f};

    // staging: thread t -> row rowbase+(t>>2), k-cols (t&3)*8..+8 (16 B)
    const unsigned short* xs = xb + (size_t)(rowbase + (t >> 2)) * CD + (t & 3) * 8;
    short* d0 = &As[0][t * 8];
    short* d1 = &As[1][t * 8];

    async16(d0, xs);                       // s=0
    __syncthreads();

#pragma unroll
    for (int s = 0; s < 8; ++s) {          // K=256, BK=32
        if (s < 7) async16((s & 1) ? d0 : d1, xs + (s + 1) * 32);
        bf16x8 bfr[4];
#pragma unroll
        for (int j = 0; j < 4; ++j)
            bfr[j] = *(const bf16x8*)(Wfrag +
                      ((size_t)((T * 8 + s) * 8 + ngb + j) * 64 + L) * 8);
        const short* Ab = As[s & 1];
#pragma unroll
        for (int i = 0; i < 4; ++i) {
            bf16x8 af = *(const bf16x8*)(Ab + (i * 16 + lrow) * 32 + quad * 8);
#pragma unroll
            for (int j = 0; j < 4; ++j)
                acc[i][j] = __builtin_amdgcn_mfma_f32_16x16x32_bf16(af, bfr[j], acc[i][j], 0, 0, 0);
        }
        __syncthreads();                   // drains prefetch + LDS
    }

#pragma unroll
    for (int i = 0; i < 4; ++i) {
#pragma unroll
        for (int r = 0; r < 4; ++r) {
            int row = rowbase + i * 16 + quad * 4 + r;
            if (g == 0) {
                int yy = (row >> 6) & 63, xx = row & 63;
                int cy = min(max(yy, 3), 60), cx = min(max(xx, 3), 60);
                int qidx = (yy - cy + 3) * 7 + (xx - cx + 3);
#pragma unroll
                for (int j = 0; j < 4; ++j) {
                    int c = wave * 64 + j * 16 + lrow;
                    QA[(size_t)row * CD + c] = bfbits(acc[i][j][r] + pe[qidx * 256 + c]);
                }
            } else if (g == 1) {
#pragma unroll
                for (int j = 0; j < 4; ++j) {
                    int c = wave * 64 + j * 16 + lrow;
                    Kd[(size_t)row * CD + c] = bfbits(acc[i][j][r] * QSCALE);
                }
            } else {
#pragma unroll
                for (int j = 0; j < 4; ++j) {
                    int c = wave * 64 + j * 16 + lrow;
                    Vt[(size_t)c * 16384 + row + 3] = bfbits(acc[i][j][r]);
                }
            }
        }
    }
}

// ---------------------------------------------------------------------------
// Kernel 2: MFMA local attention (r10 structure, unchanged logic).
// Unit = (16-position x-run, 1 head), 1 wave/unit, 4 units/block.
// ---------------------------------------------------------------------------
__global__ __launch_bounds__(256) void attn_mfma(
    unsigned short* QA,                      // bf16 [pos][256]; Q in, A out
    const unsigned short* __restrict__ Kd,   // bf16 [pos][256], pre-scaled
    const unsigned short* __restrict__ Vt,   // bf16 [ch][16384], +3 shift
    const __hip_bfloat16* __restrict__ pebf) // [h*4+Tn][64][8], pre-scaled
{
    __shared__ float qpes[4][16 * 64];
    __shared__ __align__(16) unsigned short ps[4][16 * 40];
    const int t = threadIdx.x, w = t >> 6, L = t & 63;
    const int lrow = L & 15, quad = L >> 4;
    const int id = blockIdx.x * 4 + w;
    const int tile = id >> 3, h = id & 7;
    const int pos0 = tile * 16;
    const int x0 = pos0 & 63;
    const int yy = (pos0 >> 6) & 63, bb = pos0 >> 12;
    const int cy = min(max(yy, 3), 60);

    int cxr[4];
#pragma unroll
    for (int r = 0; r < 4; ++r)
        cxr[r] = min(max(x0 + quad * 4 + r, 3), 60) - x0;

    const int kc0 = min(max(x0 - 3 + lrow, 0), 63);
    const int kc1 = min(max(x0 + 13 + lrow, 0), 63);

    const bf16x8 qa = *(const bf16x8*)(QA + (size_t)(pos0 + lrow) * 256 + h * 32 + quad * 8);

    float* qp = qpes[w];
    const f32x4 zero = {0.f, 0.f, 0.f, 0.f};
#pragma unroll
    for (int Tn = 0; Tn < 4; ++Tn) {
        bf16x8 bp = *(const bf16x8*)(pebf + ((size_t)((h * 4 + Tn) * 64 + L)) * 8);
        f32x4 c = __builtin_amdgcn_mfma_f32_16x16x32_bf16(qa, bp, zero, 0, 0, 0);
#pragma unroll
        for (int r = 0; r < 4; ++r)
            qp[(quad * 4 + r) * 64 + Tn * 16 + lrow] = c[r];
    }
    __builtin_amdgcn_s_waitcnt(0xc07f);

    float lacc[4] = {0.f, 0.f, 0.f, 0.f};
    f32x4 o0 = zero, o1 = zero;
    unsigned short* pw = ps[w];
    int rowpos = bb * 4096 + (cy - 3) * 64;

    for (int dy = 0; dy < 7; ++dy, rowpos += 64) {
        const bf16x8 bk0 = *(const bf16x8*)(Kd + (size_t)(rowpos + kc0) * 256 + h * 32 + quad * 8);
        const bf16x8 bk1 = *(const bf16x8*)(Kd + (size_t)(rowpos + kc1) * 256 + h * 32 + quad * 8);
        f32x4 sc0 = __builtin_amdgcn_mfma_f32_16x16x32_bf16(qa, bk0, zero, 0, 0, 0);
        f32x4 sc1 = __builtin_amdgcn_mfma_f32_16x16x32_bf16(qa, bk1, zero, 0, 0, 0);
        const int dy7 = dy * 7;
#pragma unroll
        for (int r = 0; r < 4; ++r) {
            const int i = quad * 4 + r;
            {
                int dx3 = lrow - cxr[r];
                float qpe = qp[i * 64 + dy7 + min(max(dx3, 0), 6)];
                float e = exp2f(sc0[r] + qpe);
                float p = ((unsigned)dx3 <= 6u) ? e : 0.f;
                lacc[r] += p;
                pw[i * 40 + lrow] = bfbits(p);
            }
            {
                int dx3 = 16 + lrow - cxr[r];
                float qpe = qp[i * 64 + dy7 + min(max(dx3, 0), 6)];
                float e = exp2f(sc1[r] + qpe);
                float p = ((unsigned)dx3 <= 6u) ? e : 0.f;
                lacc[r] += p;
                pw[i * 40 + 16 + lrow] = bfbits(p);
            }
        }
        __builtin_amdgcn_s_waitcnt(0xc07f);
        const bf16x8 pa = *(const bf16x8*)(pw + lrow * 40 + quad * 8);
        const bf16x8 bv0 = *(const bf16x8*)(Vt + (size_t)(h * 32 + lrow) * 16384 + rowpos + x0 + quad * 8);
        const bf16x8 bv1 = *(const bf16x8*)(Vt + (size_t)(h * 32 + 16 + lrow) * 16384 + rowpos + x0 + quad * 8);
        o0 = __builtin_amdgcn_mfma_f32_16x16x32_bf16(pa, bv0, o0, 0, 0, 0);
        o1 = __builtin_amdgcn_mfma_f32_16x16x32_bf16(pa, bv1, o1, 0, 0, 0);
    }

#pragma unroll
    for (int r = 0; r < 4; ++r) {
        float v = lacc[r];
        v += dpp_mov<0xB1>(v);
        v += dpp_mov<0x4E>(v);
        v += swz<0x101F>(v);
        v += swz<0x201F>(v);
        const float inv = 1.f / (v + 1e-8f);
        const int row = pos0 + quad * 4 + r;
        QA[(size_t)row * 256 + h * 32 + lrow]      = bfbits(o0[r] * inv);
        QA[(size_t)row * 256 + h * 32 + 16 + lrow] = bfbits(o1[r] * inv);
    }
}

// ---------------------------------------------------------------------------
// Kernel 3: output projection A(bf16) @ Wo -> out f32.
// 32-row x 256-col blocks, grid 512 (2 blocks/CU). Wave w = 32 rows x 64
// cols = 2x4 frags. Async gll staging (threads t<128), double-buffered.
// ---------------------------------------------------------------------------
__global__ __launch_bounds__(256, 4) void oproj_mfma(
    const unsigned short* __restrict__ A,     // QA bf16 [NPOS][256]
    const __hip_bfloat16* __restrict__ Wofrag,
    float* __restrict__ out)
{
    __shared__ __align__(16) short As[2][32 * 32];
    const int t = threadIdx.x;
    const int rowbase = blockIdx.x * 32;
    const int L = t & 63;
    const int wave = t >> 6;
    const int quad = L >> 4, lrow = L & 15;
    const int T = wave >> 1;
    const int ngb = (wave & 1) * 4;

    f32x4 acc[2][4];
#pragma unroll
    for (int i = 0; i < 2; ++i)
#pragma unroll
        for (int j = 0; j < 4; ++j) acc[i][j] = (f32x4){0.f, 0.f, 0.f, 0.f};

    const unsigned short* asrc = A + (size_t)(rowbase + (t >> 2)) * CD + (t & 3) * 8;
    short* d0 = &As[0][t * 8];
    short* d1 = &As[1][t * 8];

    if (t < 128) async16(d0, asrc);        // s=0 (32 rows x 32 k = 2 KB)
    __syncthreads();

#pragma unroll
    for (int s = 0; s < 8; ++s) {
        if (s < 7 && t < 128) async16((s & 1) ? d0 : d1, asrc + (s + 1) * 32);
        bf16x8 bfr[4];
#pragma unroll
        for (int j = 0; j < 4; ++j)
            bfr[j] = *(const bf16x8*)(Wofrag +
                      ((size_t)((T * 8 + s) * 8 + ngb + j) * 64 + L) * 8);
        const short* Ab = As[s & 1];
#pragma unroll
        for (int i = 0; i < 2; ++i) {
            bf16x8 af = *(const bf16x8*)(Ab + (i * 16 + lrow) * 32 + quad * 8);
#pragma unroll
            for (int j = 0; j < 4; ++j)
                acc[i][j] = __builtin_amdgcn_mfma_f32_16x16x32_bf16(af, bfr[j], acc[i][j], 0, 0, 0);
        }
        __syncthreads();
    }

#pragma unroll
    for (int i = 0; i < 2; ++i)
#pragma unroll
        for (int r = 0; r < 4; ++r) {
            int row = rowbase + i * 16 + quad * 4 + r;
#pragma unroll
            for (int j = 0; j < 4; ++j) {
                int c = wave * 64 + j * 16 + lrow;
                out[(size_t)row * CD + c] = acc[i][j][r];
            }
        }
}

// ---------------------------------------------------------------------------
// Memory plan (ws is ~256 MiB per the 262144 KB re-poison fill; use 33 MB):
//   ws[ 0,  8MB): QA bf16 (Q+pe_q -> in-place attn output A)
//   ws[ 8, 16MB): Kd bf16 (QSCALE-folded)
//   ws[16, 24MB): Vt bf16 transposed [ch][16384] (+3 shift; 4KB pad after)
//   ws[24MB+4KB, +8MB): xb bf16 (x converted)
//   ws[32MB+8KB, +544KB): Wfrag 384KB | pebf 32KB | Wofrag 128KB
//   d_out: final f32 output only (no aliasing).
// ---------------------------------------------------------------------------
extern "C" void kernel_launch(void* const* d_in, const int* in_sizes, int n_in,
                              void* d_out, int out_size, void* d_ws, size_t ws_size,
                              hipStream_t stream)
{
    const float* x  = (const float*)d_in[0];
    const float* Wq = (const float*)d_in[1];
    const float* Wk = (const float*)d_in[2];
    const float* Wv = (const float*)d_in[3];
    const float* Wo = (const float*)d_in[4];
    const float* pe = (const float*)d_in[5];
    float* out = (float*)d_out;

    char* ws = (char*)d_ws;
    unsigned short* QA = (unsigned short*)ws;
    unsigned short* Kd = (unsigned short*)(ws + (8u << 20));
    unsigned short* Vt = (unsigned short*)(ws + (16u << 20));
    unsigned short* xb = (unsigned short*)(ws + (24u << 20) + 4096);
    char* fr = ws + (32u << 20) + 8192;
    __hip_bfloat16* Wfrag  = (__hip_bfloat16*)fr;
    __hip_bfloat16* pebf   = (__hip_bfloat16*)(fr + (384u << 10));
    __hip_bfloat16* Wofrag = (__hip_bfloat16*)(fr + (416u << 10));

    convertx_kernel<<<2048, 256, 0, stream>>>(x, xb);
    convert1_kernel<<<136, 256, 0, stream>>>(Wq, Wk, Wv, Wo, pe, Wfrag, pebf, Wofrag);
    qkv_mfma<<<dim3(256, 3), 256, 0, stream>>>(xb, Wfrag, pe, QA, Kd, Vt);
    attn_mfma<<<2048, 256, 0, stream>>>(QA, Kd, Vt, pebf);
    oproj_mfma<<<512, 256, 0, stream>>>(QA, Wofrag, out);
}

// Round 12
// 138.275 us; speedup vs baseline: 1.2457x; 1.0012x over previous
//
#include <hip/hip_runtime.h>
#include <hip/hip_bf16.h>

// B=4, Y=64, X=64, C=256, H=8, F=32, 7x7 window (S=49). All I/O is FLOAT32.
static constexpr int NPOS = 4 * 64 * 64;   // 16384 rows
static constexpr int CD   = 256;
// softmax scale (1/sqrt(32)) * log2(e), folded into K and pe_k at pack time
#define QSCALE (0.17677669529663687f * 1.4426950408889634f)

typedef __attribute__((ext_vector_type(8))) short bf16x8;   // MFMA A/B frag
typedef __attribute__((ext_vector_type(4))) float f32x4;    // MFMA C/D frag

__device__ __forceinline__ unsigned short bfbits(float f) {
    union { __hip_bfloat16 h; unsigned short u; } cv;
    cv.h = __float2bfloat16(f);
    return cv.u;
}
__device__ __forceinline__ unsigned int packbf2(float lo, float hi) {
    union { __hip_bfloat162 h; unsigned int u; } cv;
    cv.h.x = __float2bfloat16(lo);
    cv.h.y = __float2bfloat16(hi);
    return cv.u;
}
__device__ __forceinline__ uint4 pack8(float4 a, float4 b) {
    uint4 u;
    u.x = packbf2(a.x, a.y); u.y = packbf2(a.z, a.w);
    u.z = packbf2(b.x, b.y); u.w = packbf2(b.z, b.w);
    return u;
}
template<int CTRL>
__device__ __forceinline__ float dpp_mov(float v) {
    return __int_as_float(
        __builtin_amdgcn_update_dpp(0, __float_as_int(v), CTRL, 0xF, 0xF, true));
}
template<int IMM>
__device__ __forceinline__ float swz(float v) {
    return __int_as_float(__builtin_amdgcn_ds_swizzle(__float_as_int(v), IMM));
}
// async global->LDS copy, 16 B per lane (global_load_lds_dwordx4).
__device__ __forceinline__ void async16(void* lds, const void* g) {
    __builtin_amdgcn_global_load_lds(
        (const __attribute__((address_space(1))) unsigned int*)g,
        (__attribute__((address_space(3))) unsigned int*)lds, 16, 0, 0);
}

// ---------------------------------------------------------------------------
// convert: blocks 0..135  -> Wfrag (384KB) + pebf (32KB) + Wofrag (128KB);
//          blocks 136..2183 -> x f32 -> xb bf16 (8 MB), 8 elems/thread.
// ---------------------------------------------------------------------------
__global__ __launch_bounds__(256) void convert_kernel(
    const float* __restrict__ x,  unsigned short* __restrict__ xb,
    const float* __restrict__ Wq, const float* __restrict__ Wk,
    const float* __restrict__ Wv, const float* __restrict__ Wo,
    const float* __restrict__ pe,
    __hip_bfloat16* __restrict__ Wfrag,
    __hip_bfloat16* __restrict__ pebf,
    __hip_bfloat16* __restrict__ Wofrag)
{
    if (blockIdx.x >= 136) {
        int t = (blockIdx.x - 136) * 256 + threadIdx.x;
        const float4* s = (const float4*)x + (size_t)t * 2;
        float4 a = s[0], b = s[1];
        ((uint4*)xb)[t] = pack8(a, b);
        return;
    }
    int t = blockIdx.x * 256 + threadIdx.x;
    if (t < 24576) {
        int L = t & 63, ng = (t >> 6) & 7, s = (t >> 9) & 7, T = t >> 12;
        int mat = T >> 1;
        const float* src = (mat == 0) ? Wq : (mat == 1) ? Wk : Wv;
        int ncol  = (T & 1) * 128 + ng * 16 + (L & 15);
        int kbase = s * 32 + (L >> 4) * 8;
        __hip_bfloat16* dst = Wfrag + ((size_t)((T * 8 + s) * 8 + ng) * 64 + L) * 8;
#pragma unroll
        for (int j = 0; j < 8; ++j)
            dst[j] = __float2bfloat16(src[(kbase + j) * 256 + ncol]);
    } else if (t < 26624) {
        int u = t - 24576;
        int L = u & 63, Tn = (u >> 6) & 3, h = u >> 8;
        int s = Tn * 16 + (L & 15);
        int kbase = (L >> 4) * 8;
        __hip_bfloat16* dst = pebf + ((size_t)((h * 4 + Tn) * 64 + L)) * 8;
#pragma unroll
        for (int j = 0; j < 8; ++j) {
            float v = (s < 49) ? pe[s * 256 + h * 32 + kbase + j] * QSCALE : 0.f;
            dst[j] = __float2bfloat16(v);
        }
    } else if (t < 34816) {
        int u = t - 26624;
        int L = u & 63, ng = (u >> 6) & 7, s = (u >> 9) & 7, T = (u >> 12) & 1;
        int ncol  = T * 128 + ng * 16 + (L & 15);
        int kbase = s * 32 + (L >> 4) * 8;
        __hip_bfloat16* dst = Wofrag + ((size_t)((T * 8 + s) * 8 + ng) * 64 + L) * 8;
#pragma unroll
        for (int j = 0; j < 8; ++j)
            dst[j] = __float2bfloat16(Wo[(kbase + j) * 256 + ncol]);
    }
}

// ---------------------------------------------------------------------------
// Kernel 1: Q/K GEMM from xb. grid=(256, 2): g=0->Q(+pe_q)->QA, 1->K*QSCALE.
// Async gll staging, double-buffered, 64-row x 256-col blocks.
// ---------------------------------------------------------------------------
__global__ __launch_bounds__(256, 4) void qk_mfma(
    const unsigned short* __restrict__ xb,
    const __hip_bfloat16* __restrict__ Wfrag,
    const float* __restrict__ pe,
    unsigned short* __restrict__ QA,
    unsigned short* __restrict__ Kd)
{
    __shared__ __align__(16) short As[2][64 * 32];
    const int t = threadIdx.x;
    const int rowbase = blockIdx.x * 64;
    const int g = blockIdx.y;
    const int L = t & 63;
    const int wave = t >> 6;
    const int quad = L >> 4, lrow = L & 15;
    const int T = g * 2 + (wave >> 1);
    const int ngb = (wave & 1) * 4;

    f32x4 acc[4][4];
#pragma unroll
    for (int i = 0; i < 4; ++i)
#pragma unroll
        for (int j = 0; j < 4; ++j) acc[i][j] = (f32x4){0.f, 0.f, 0.f, 0.f};

    const unsigned short* xs = xb + (size_t)(rowbase + (t >> 2)) * CD + (t & 3) * 8;
    short* d0 = &As[0][t * 8];
    short* d1 = &As[1][t * 8];

    async16(d0, xs);
    __syncthreads();

#pragma unroll
    for (int s = 0; s < 8; ++s) {
        if (s < 7) async16((s & 1) ? d0 : d1, xs + (s + 1) * 32);
        bf16x8 bfr[4];
#pragma unroll
        for (int j = 0; j < 4; ++j)
            bfr[j] = *(const bf16x8*)(Wfrag +
                      ((size_t)((T * 8 + s) * 8 + ngb + j) * 64 + L) * 8);
        const short* Ab = As[s & 1];
#pragma unroll
        for (int i = 0; i < 4; ++i) {
            bf16x8 af = *(const bf16x8*)(Ab + (i * 16 + lrow) * 32 + quad * 8);
#pragma unroll
            for (int j = 0; j < 4; ++j)
                acc[i][j] = __builtin_amdgcn_mfma_f32_16x16x32_bf16(af, bfr[j], acc[i][j], 0, 0, 0);
        }
        __syncthreads();
    }

#pragma unroll
    for (int i = 0; i < 4; ++i) {
#pragma unroll
        for (int r = 0; r < 4; ++r) {
            int row = rowbase + i * 16 + quad * 4 + r;
            if (g == 0) {
                int yy = (row >> 6) & 63, xx = row & 63;
                int cy = min(max(yy, 3), 60), cx = min(max(xx, 3), 60);
                int qidx = (yy - cy + 3) * 7 + (xx - cx + 3);
#pragma unroll
                for (int j = 0; j < 4; ++j) {
                    int c = wave * 64 + j * 16 + lrow;
                    QA[(size_t)row * CD + c] = bfbits(acc[i][j][r] + pe[qidx * 256 + c]);
                }
            } else {
#pragma unroll
                for (int j = 0; j < 4; ++j) {
                    int c = wave * 64 + j * 16 + lrow;
                    Kd[(size_t)row * CD + c] = bfbits(acc[i][j][r] * QSCALE);
                }
            }
        }
    }
}

// ---------------------------------------------------------------------------
// Kernel 1b: V GEMM -> Vt TRANSPOSED [ch][16384] (no shift). Epilogue goes
// through an LDS transpose tile so global stores are COALESCED short4 runs
// (was: 64 scattered 2-B stores/thread at 32KB stride — the r11 bottleneck).
// ---------------------------------------------------------------------------
__global__ __launch_bounds__(256, 3) void vproj_mfma(
    const unsigned short* __restrict__ xb,
    const __hip_bfloat16* __restrict__ Wfrag,
    unsigned short* __restrict__ Vt)
{
    __shared__ __align__(16) short As[2][64 * 32];
    __shared__ __align__(8) unsigned short vt[256 * 68];  // [c][row], pad 68
    const int t = threadIdx.x;
    const int rowbase = blockIdx.x * 64;
    const int L = t & 63;
    const int wave = t >> 6;
    const int quad = L >> 4, lrow = L & 15;
    const int T = 4 + (wave >> 1);                // V weight tiles
    const int ngb = (wave & 1) * 4;

    f32x4 acc[4][4];
#pragma unroll
    for (int i = 0; i < 4; ++i)
#pragma unroll
        for (int j = 0; j < 4; ++j) acc[i][j] = (f32x4){0.f, 0.f, 0.f, 0.f};

    const unsigned short* xs = xb + (size_t)(rowbase + (t >> 2)) * CD + (t & 3) * 8;
    short* d0 = &As[0][t * 8];
    short* d1 = &As[1][t * 8];

    async16(d0, xs);
    __syncthreads();

#pragma unroll
    for (int s = 0; s < 8; ++s) {
        if (s < 7) async16((s & 1) ? d0 : d1, xs + (s + 1) * 32);
        bf16x8 bfr[4];
#pragma unroll
        for (int j = 0; j < 4; ++j)
            bfr[j] = *(const bf16x8*)(Wfrag +
                      ((size_t)((T * 8 + s) * 8 + ngb + j) * 64 + L) * 8);
        const short* Ab = As[s & 1];
#pragma unroll
        for (int i = 0; i < 4; ++i) {
            bf16x8 af = *(const bf16x8*)(Ab + (i * 16 + lrow) * 32 + quad * 8);
#pragma unroll
            for (int j = 0; j < 4; ++j)
                acc[i][j] = __builtin_amdgcn_mfma_f32_16x16x32_bf16(af, bfr[j], acc[i][j], 0, 0, 0);
        }
        __syncthreads();
    }

    // acc -> LDS transpose tile: vt[c][row], short2 per row-pair (2-way bank)
#pragma unroll
    for (int i = 0; i < 4; ++i) {
#pragma unroll
        for (int j = 0; j < 4; ++j) {
            int c = wave * 64 + j * 16 + lrow;
            int row0 = i * 16 + quad * 4;
            *(unsigned int*)&vt[c * 68 + row0] =
                packbf2(__uint_as_float(0), 0.f), // placeholder avoided below
            *(unsigned int*)&vt[c * 68 + row0] =
                (unsigned int)bfbits(acc[i][j][0]) | ((unsigned int)bfbits(acc[i][j][1]) << 16);
            *(unsigned int*)&vt[c * 68 + row0 + 2] =
                (unsigned int)bfbits(acc[i][j][2]) | ((unsigned int)bfbits(acc[i][j][3]) << 16);
        }
    }
    __syncthreads();

    // coalesced store: 16 passes; group of 16 threads covers one c (64 rows)
    const int grp = t >> 4, lig = t & 15;        // 16 groups, lane-in-group
    const int row_off = lig * 4;
#pragma unroll
    for (int pass = 0; pass < 16; ++pass) {
        int c = pass * 16 + grp;
        *(ushort4*)(Vt + (size_t)c * 16384 + rowbase + row_off) =
            *(const ushort4*)&vt[c * 68 + row_off];
    }
}

// ---------------------------------------------------------------------------
// Kernel 2: MFMA local attention. Patch base x0-8 (keeps Vt loads 16-B
// aligned with UNSHIFTED Vt; underflow reads land in Kd tail, masked by P=0).
// Unit = (16-position x-run, 1 head), 1 wave/unit, 4 units/block.
// ---------------------------------------------------------------------------
__global__ __launch_bounds__(256) void attn_mfma(
    unsigned short* QA,                      // bf16 [pos][256]; Q in, A out
    const unsigned short* __restrict__ Kd,   // bf16 [pos][256], pre-scaled
    const unsigned short* __restrict__ Vt,   // bf16 [ch][16384], no shift
    const __hip_bfloat16* __restrict__ pebf) // [h*4+Tn][64][8], pre-scaled
{
    __shared__ float qpes[4][16 * 64];
    __shared__ __align__(16) unsigned short ps[4][16 * 40];
    const int t = threadIdx.x, w = t >> 6, L = t & 63;
    const int lrow = L & 15, quad = L >> 4;
    const int id = blockIdx.x * 4 + w;
    const int tile = id >> 3, h = id & 7;
    const int pos0 = tile * 16;
    const int x0 = pos0 & 63;
    const int yy = (pos0 >> 6) & 63, bb = pos0 >> 12;
    const int cy = min(max(yy, 3), 60);

    // band center in patch coords (patch base = x0-8): cxr = cx - x0 + 5
    int cxr[4];
#pragma unroll
    for (int r = 0; r < 4; ++r)
        cxr[r] = min(max(x0 + quad * 4 + r, 3), 60) - x0 + 5;

    const int kc0 = min(max(x0 - 8 + lrow, 0), 63);
    const int kc1 = min(max(x0 + 8 + lrow, 0), 63);

    const bf16x8 qa = *(const bf16x8*)(QA + (size_t)(pos0 + lrow) * 256 + h * 32 + quad * 8);

    float* qp = qpes[w];
    const f32x4 zero = {0.f, 0.f, 0.f, 0.f};
#pragma unroll
    for (int Tn = 0; Tn < 4; ++Tn) {
        bf16x8 bp = *(const bf16x8*)(pebf + ((size_t)((h * 4 + Tn) * 64 + L)) * 8);
        f32x4 c = __builtin_amdgcn_mfma_f32_16x16x32_bf16(qa, bp, zero, 0, 0, 0);
#pragma unroll
        for (int r = 0; r < 4; ++r)
            qp[(quad * 4 + r) * 64 + Tn * 16 + lrow] = c[r];
    }
    __builtin_amdgcn_s_waitcnt(0xc07f);

    float lacc[4] = {0.f, 0.f, 0.f, 0.f};
    f32x4 o0 = zero, o1 = zero;
    unsigned short* pw = ps[w];
    int rowpos = bb * 4096 + (cy - 3) * 64;

    for (int dy = 0; dy < 7; ++dy, rowpos += 64) {
        const bf16x8 bk0 = *(const bf16x8*)(Kd + (size_t)(rowpos + kc0) * 256 + h * 32 + quad * 8);
        const bf16x8 bk1 = *(const bf16x8*)(Kd + (size_t)(rowpos + kc1) * 256 + h * 32 + quad * 8);
        f32x4 sc0 = __builtin_amdgcn_mfma_f32_16x16x32_bf16(qa, bk0, zero, 0, 0, 0);
        f32x4 sc1 = __builtin_amdgcn_mfma_f32_16x16x32_bf16(qa, bk1, zero, 0, 0, 0);
        const int dy7 = dy * 7;
#pragma unroll
        for (int r = 0; r < 4; ++r) {
            const int i = quad * 4 + r;
            {
                int dx3 = lrow - cxr[r];
                float qpe = qp[i * 64 + dy7 + min(max(dx3, 0), 6)];
                float e = exp2f(sc0[r] + qpe);
                float p = ((unsigned)dx3 <= 6u) ? e : 0.f;
                lacc[r] += p;
                pw[i * 40 + lrow] = bfbits(p);
            }
            {
                int dx3 = 16 + lrow - cxr[r];
                float qpe = qp[i * 64 + dy7 + min(max(dx3, 0), 6)];
                float e = exp2f(sc1[r] + qpe);
                float p = ((unsigned)dx3 <= 6u) ? e : 0.f;
                lacc[r] += p;
                pw[i * 40 + 16 + lrow] = bfbits(p);
            }
        }
        __builtin_amdgcn_s_waitcnt(0xc07f);
        const bf16x8 pa = *(const bf16x8*)(pw + lrow * 40 + quad * 8);
        const bf16x8 bv0 = *(const bf16x8*)(Vt + (size_t)(h * 32 + lrow) * 16384 + rowpos + x0 - 8 + quad * 8);
        const bf16x8 bv1 = *(const bf16x8*)(Vt + (size_t)(h * 32 + 16 + lrow) * 16384 + rowpos + x0 - 8 + quad * 8);
        o0 = __builtin_amdgcn_mfma_f32_16x16x32_bf16(pa, bv0, o0, 0, 0, 0);
        o1 = __builtin_amdgcn_mfma_f32_16x16x32_bf16(pa, bv1, o1, 0, 0, 0);
    }

#pragma unroll
    for (int r = 0; r < 4; ++r) {
        float v = lacc[r];
        v += dpp_mov<0xB1>(v);
        v += dpp_mov<0x4E>(v);
        v += swz<0x101F>(v);
        v += swz<0x201F>(v);
        const float inv = 1.f / (v + 1e-8f);
        const int row = pos0 + quad * 4 + r;
        QA[(size_t)row * 256 + h * 32 + lrow]      = bfbits(o0[r] * inv);
        QA[(size_t)row * 256 + h * 32 + 16 + lrow] = bfbits(o1[r] * inv);
    }
}

// ---------------------------------------------------------------------------
// Kernel 3: output projection A(bf16) @ Wo -> out f32. 32-row tiles, grid
// 512; async gll staging (t<128), double-buffered.
// ---------------------------------------------------------------------------
__global__ __launch_bounds__(256, 4) void oproj_mfma(
    const unsigned short* __restrict__ A,
    const __hip_bfloat16* __restrict__ Wofrag,
    float* __restrict__ out)
{
    __shared__ __align__(16) short As[2][32 * 32];
    const int t = threadIdx.x;
    const int rowbase = blockIdx.x * 32;
    const int L = t & 63;
    const int wave = t >> 6;
    const int quad = L >> 4, lrow = L & 15;
    const int T = wave >> 1;
    const int ngb = (wave & 1) * 4;

    f32x4 acc[2][4];
#pragma unroll
    for (int i = 0; i < 2; ++i)
#pragma unroll
        for (int j = 0; j < 4; ++j) acc[i][j] = (f32x4){0.f, 0.f, 0.f, 0.f};

    const unsigned short* asrc = A + (size_t)(rowbase + (t >> 2)) * CD + (t & 3) * 8;
    short* d0 = &As[0][t * 8];
    short* d1 = &As[1][t * 8];

    if (t < 128) async16(d0, asrc);
    __syncthreads();

#pragma unroll
    for (int s = 0; s < 8; ++s) {
        if (s < 7 && t < 128) async16((s & 1) ? d0 : d1, asrc + (s + 1) * 32);
        bf16x8 bfr[4];
#pragma unroll
        for (int j = 0; j < 4; ++j)
            bfr[j] = *(const bf16x8*)(Wofrag +
                      ((size_t)((T * 8 + s) * 8 + ngb + j) * 64 + L) * 8);
        const short* Ab = As[s & 1];
#pragma unroll
        for (int i = 0; i < 2; ++i) {
            bf16x8 af = *(const bf16x8*)(Ab + (i * 16 + lrow) * 32 + quad * 8);
#pragma unroll
            for (int j = 0; j < 4; ++j)
                acc[i][j] = __builtin_amdgcn_mfma_f32_16x16x32_bf16(af, bfr[j], acc[i][j], 0, 0, 0);
        }
        __syncthreads();
    }

#pragma unroll
    for (int i = 0; i < 2; ++i)
#pragma unroll
        for (int r = 0; r < 4; ++r) {
            int row = rowbase + i * 16 + quad * 4 + r;
#pragma unroll
            for (int j = 0; j < 4; ++j) {
                int c = wave * 64 + j * 16 + lrow;
                out[(size_t)row * CD + c] = acc[i][j][r];
            }
        }
}

// ---------------------------------------------------------------------------
// Memory plan (ws ~256 MiB; we use ~33 MB):
//   ws[ 0,  8MB): QA bf16 (Q+pe_q -> in-place attn output A)
//   ws[ 8, 16MB): Kd bf16 (QSCALE-folded; its tail also absorbs Vt underflow)
//   ws[16, 24MB): Vt bf16 transposed [ch][16384], unshifted; 4KB pad after
//   ws[24MB+4KB, +8MB): xb bf16
//   ws[32MB+8KB, +544KB): Wfrag 384KB | pebf 32KB | Wofrag 128KB
// ---------------------------------------------------------------------------
extern "C" void kernel_launch(void* const* d_in, const int* in_sizes, int n_in,
                              void* d_out, int out_size, void* d_ws, size_t ws_size,
                              hipStream_t stream)
{
    const float* x  = (const float*)d_in[0];
    const float* Wq = (const float*)d_in[1];
    const float* Wk = (const float*)d_in[2];
    const float* Wv = (const float*)d_in[3];
    const float* Wo = (const float*)d_in[4];
    const float* pe = (const float*)d_in[5];
    float* out = (float*)d_out;

    char* ws = (char*)d_ws;
    unsigned short* QA = (unsigned short*)ws;
    unsigned short* Kd = (unsigned short*)(ws + (8u << 20));
    unsigned short* Vt = (unsigned short*)(ws + (16u << 20));
    unsigned short* xb = (unsigned short*)(ws + (24u << 20) + 4096);
    char* fr = ws + (32u << 20) + 8192;
    __hip_bfloat16* Wfrag  = (__hip_bfloat16*)fr;
    __hip_bfloat16* pebf   = (__hip_bfloat16*)(fr + (384u << 10));
    __hip_bfloat16* Wofrag = (__hip_bfloat16*)(fr + (416u << 10));

    convert_kernel<<<2184, 256, 0, stream>>>(x, xb, Wq, Wk, Wv, Wo, pe,
                                             Wfrag, pebf, Wofrag);
    qk_mfma<<<dim3(256, 2), 256, 0, stream>>>(xb, Wfrag, pe, QA, Kd);
    vproj_mfma<<<256, 256, 0, stream>>>(xb, Wfrag, Vt);
    attn_mfma<<<2048, 256, 0, stream>>>(QA, Kd, Vt, pebf);
    oproj_mfma<<<512, 256, 0, stream>>>(QA, Wofrag, out);
}

// Round 13
// 128.614 us; speedup vs baseline: 1.3392x; 1.0751x over previous
//
#include <hip/hip_runtime.h>
#include <hip/hip_bf16.h>

// B=4, Y=64, X=64, C=256, H=8, F=32, 7x7 window (S=49). All I/O is FLOAT32.
// NOTE (r12 post-mortem): measured dur_us includes ~55us of harness
// restore/re-poison (256MiB fill) — kernel-side budget is dur_us - ~55.
static constexpr int NPOS = 4 * 64 * 64;   // 16384 rows
static constexpr int CD   = 256;
#define QSCALE (0.17677669529663687f * 1.4426950408889634f)  // 1/sqrt(32)*log2e

typedef __attribute__((ext_vector_type(8))) short bf16x8;   // MFMA A/B frag
typedef __attribute__((ext_vector_type(4))) float f32x4;    // MFMA C/D frag

__device__ __forceinline__ unsigned short bfbits(float f) {
    union { __hip_bfloat16 h; unsigned short u; } cv;
    cv.h = __float2bfloat16(f);
    return cv.u;
}
__device__ __forceinline__ unsigned int packbf2(float lo, float hi) {
    union { __hip_bfloat162 h; unsigned int u; } cv;
    cv.h.x = __float2bfloat16(lo);
    cv.h.y = __float2bfloat16(hi);
    return cv.u;
}
__device__ __forceinline__ uint4 pack8(float4 a, float4 b) {
    uint4 u;
    u.x = packbf2(a.x, a.y); u.y = packbf2(a.z, a.w);
    u.z = packbf2(b.x, b.y); u.w = packbf2(b.z, b.w);
    return u;
}
template<int CTRL>
__device__ __forceinline__ float dpp_mov(float v) {
    return __int_as_float(
        __builtin_amdgcn_update_dpp(0, __float_as_int(v), CTRL, 0xF, 0xF, true));
}
template<int IMM>
__device__ __forceinline__ float swz(float v) {
    return __int_as_float(__builtin_amdgcn_ds_swizzle(__float_as_int(v), IMM));
}
// async global->LDS, 16 B/lane (global_load_lds_dwordx4)
__device__ __forceinline__ void async16(void* lds, const void* g) {
    __builtin_amdgcn_global_load_lds(
        (const __attribute__((address_space(1))) unsigned int*)g,
        (__attribute__((address_space(3))) unsigned int*)lds, 16, 0, 0);
}

// ---------------------------------------------------------------------------
// convert: Wfrag (Wq|Wk|Wv b-frag bf16, 384KB) + pebf (pe^T b-frag,
// QSCALE-folded, 32KB) + Wofrag (128KB). 136 blocks x 256.
// ---------------------------------------------------------------------------
__global__ __launch_bounds__(256) void convert_kernel(
    const float* __restrict__ Wq, const float* __restrict__ Wk,
    const float* __restrict__ Wv, const float* __restrict__ Wo,
    const float* __restrict__ pe,
    __hip_bfloat16* __restrict__ Wfrag,
    __hip_bfloat16* __restrict__ pebf,
    __hip_bfloat16* __restrict__ Wofrag)
{
    int t = blockIdx.x * 256 + threadIdx.x;
    if (t < 24576) {
        int L = t & 63, ng = (t >> 6) & 7, s = (t >> 9) & 7, T = t >> 12;
        int mat = T >> 1;
        const float* src = (mat == 0) ? Wq : (mat == 1) ? Wk : Wv;
        int ncol  = (T & 1) * 128 + ng * 16 + (L & 15);
        int kbase = s * 32 + (L >> 4) * 8;
        __hip_bfloat16* dst = Wfrag + ((size_t)((T * 8 + s) * 8 + ng) * 64 + L) * 8;
#pragma unroll
        for (int j = 0; j < 8; ++j)
            dst[j] = __float2bfloat16(src[(kbase + j) * 256 + ncol]);
    } else if (t < 26624) {
        int u = t - 24576;
        int L = u & 63, Tn = (u >> 6) & 3, h = u >> 8;
        int s = Tn * 16 + (L & 15);
        int kbase = (L >> 4) * 8;
        __hip_bfloat16* dst = pebf + ((size_t)((h * 4 + Tn) * 64 + L)) * 8;
#pragma unroll
        for (int j = 0; j < 8; ++j) {
            float v = (s < 49) ? pe[s * 256 + h * 32 + kbase + j] * QSCALE : 0.f;
            dst[j] = __float2bfloat16(v);
        }
    } else if (t < 34816) {
        int u = t - 26624;
        int L = u & 63, ng = (u >> 6) & 7, s = (u >> 9) & 7, T = (u >> 12) & 1;
        int ncol  = T * 128 + ng * 16 + (L & 15);
        int kbase = s * 32 + (L >> 4) * 8;
        __hip_bfloat16* dst = Wofrag + ((size_t)((T * 8 + s) * 8 + ng) * 64 + L) * 8;
#pragma unroll
        for (int j = 0; j < 8; ++j)
            dst[j] = __float2bfloat16(Wo[(kbase + j) * 256 + ncol]);
    }
}

// ---------------------------------------------------------------------------
// Kernel 1: fused QKV GEMM reading x f32 DIRECTLY (no xb pass). grid=(256,3):
// g=0->Q(+pe_q)->QA, 1->K*QSCALE->Kd, 2->V -> Vt transposed via LDS tile
// with coalesced short4 stores. LDS is a UNION: As (8KB, live in K-loop)
// and vt (35KB, live only after the last As read) share one buffer.
// ---------------------------------------------------------------------------
__global__ __launch_bounds__(256, 4) void qkv_mfma(
    const float* __restrict__ x,
    const __hip_bfloat16* __restrict__ Wfrag,
    const float* __restrict__ pe,
    unsigned short* __restrict__ QA,
    unsigned short* __restrict__ Kd,
    unsigned short* __restrict__ Vt)
{
    __shared__ __align__(16) unsigned short smem[256 * 68];  // 34.8 KB union
    short* As0 = (short*)smem;             // [64*32] bf16 tile, buffer 0
    short* As1 = As0 + 2048;               // buffer 1
    const int t = threadIdx.x;
    const int rowbase = blockIdx.x * 64;
    const int g = blockIdx.y;
    const int L = t & 63;
    const int wave = t >> 6;
    const int quad = L >> 4, lrow = L & 15;
    const int T = g * 2 + (wave >> 1);
    const int ngb = (wave & 1) * 4;

    f32x4 acc[4][4];
#pragma unroll
    for (int i = 0; i < 4; ++i)
#pragma unroll
        for (int j = 0; j < 4; ++j) acc[i][j] = (f32x4){0.f, 0.f, 0.f, 0.f};

    // staging: thread t -> row rowbase+(t>>2), k-cols (t&3)*8..+8
    const float* xsrc = x + (size_t)(rowbase + (t >> 2)) * CD + (t & 3) * 8;

    float4 f0 = ((const float4*)xsrc)[0];
    float4 f1 = ((const float4*)xsrc)[1];
    ((uint4*)As0)[t] = pack8(f0, f1);
    f0 = ((const float4*)(xsrc + 32))[0];
    f1 = ((const float4*)(xsrc + 32))[1];
    __syncthreads();

#pragma unroll
    for (int s = 0; s < 8; ++s) {          // K=256, BK=32
        bf16x8 bfr[4];
#pragma unroll
        for (int j = 0; j < 4; ++j)
            bfr[j] = *(const bf16x8*)(Wfrag +
                      ((size_t)((T * 8 + s) * 8 + ngb + j) * 64 + L) * 8);
        if (s < 7) {
            ((uint4*)((s & 1) ? As0 : As1))[t] = pack8(f0, f1);
            if (s < 6) {
                f0 = ((const float4*)(xsrc + (s + 2) * 32))[0];
                f1 = ((const float4*)(xsrc + (s + 2) * 32))[1];
            }
        }
        const short* Ab = (s & 1) ? As1 : As0;
#pragma unroll
        for (int i = 0; i < 4; ++i) {
            bf16x8 af = *(const bf16x8*)(Ab + (i * 16 + lrow) * 32 + quad * 8);
#pragma unroll
            for (int j = 0; j < 4; ++j)
                acc[i][j] = __builtin_amdgcn_mfma_f32_16x16x32_bf16(af, bfr[j], acc[i][j], 0, 0, 0);
        }
        __syncthreads();                   // also makes smem safe to repurpose
    }

    if (g == 0) {
#pragma unroll
        for (int i = 0; i < 4; ++i)
#pragma unroll
            for (int r = 0; r < 4; ++r) {
                int row = rowbase + i * 16 + quad * 4 + r;
                int yy = (row >> 6) & 63, xx = row & 63;
                int cy = min(max(yy, 3), 60), cx = min(max(xx, 3), 60);
                int qidx = (yy - cy + 3) * 7 + (xx - cx + 3);
#pragma unroll
                for (int j = 0; j < 4; ++j) {
                    int c = wave * 64 + j * 16 + lrow;
                    QA[(size_t)row * CD + c] = bfbits(acc[i][j][r] + pe[qidx * 256 + c]);
                }
            }
    } else if (g == 1) {
#pragma unroll
        for (int i = 0; i < 4; ++i)
#pragma unroll
            for (int r = 0; r < 4; ++r) {
                int row = rowbase + i * 16 + quad * 4 + r;
#pragma unroll
                for (int j = 0; j < 4; ++j) {
                    int c = wave * 64 + j * 16 + lrow;
                    Kd[(size_t)row * CD + c] = bfbits(acc[i][j][r] * QSCALE);
                }
            }
    } else {
        // LDS transpose: vt[c][row] (pad 68), then coalesced short4 stores
        unsigned short* vt = smem;
#pragma unroll
        for (int i = 0; i < 4; ++i)
#pragma unroll
            for (int j = 0; j < 4; ++j) {
                int c = wave * 64 + j * 16 + lrow;
                int row0 = i * 16 + quad * 4;
                *(unsigned int*)&vt[c * 68 + row0] =
                    (unsigned int)bfbits(acc[i][j][0]) | ((unsigned int)bfbits(acc[i][j][1]) << 16);
                *(unsigned int*)&vt[c * 68 + row0 + 2] =
                    (unsigned int)bfbits(acc[i][j][2]) | ((unsigned int)bfbits(acc[i][j][3]) << 16);
            }
        __syncthreads();
        const int grp = t >> 4, lig = t & 15;
        const int row_off = lig * 4;
#pragma unroll
        for (int pass = 0; pass < 16; ++pass) {
            int c = pass * 16 + grp;
            *(ushort4*)(Vt + (size_t)c * 16384 + rowbase + row_off) =
                *(const ushort4*)&vt[c * 68 + row_off];
        }
    }
}

// ---------------------------------------------------------------------------
// Kernel 2: MFMA local attention, dy-loop SOFTWARE-PIPELINED: bk/bv frags
// for dy+1 issued before the VALU/LDS/PV phase of dy (one full iteration of
// latency slack instead of load->use stalls 7x per wave).
// Unit = (16-pos x-run, 1 head), 1 wave/unit, 4 units/block. Patch base
// x0-8 (Vt 16B-aligned; underflow lands in Kd tail, masked by P=0).
// ---------------------------------------------------------------------------
__global__ __launch_bounds__(256) void attn_mfma(
    unsigned short* QA,
    const unsigned short* __restrict__ Kd,
    const unsigned short* __restrict__ Vt,
    const __hip_bfloat16* __restrict__ pebf)
{
    __shared__ float qpes[4][16 * 64];
    __shared__ __align__(16) unsigned short ps[4][16 * 40];
    const int t = threadIdx.x, w = t >> 6, L = t & 63;
    const int lrow = L & 15, quad = L >> 4;
    const int id = blockIdx.x * 4 + w;
    const int tile = id >> 3, h = id & 7;
    const int pos0 = tile * 16;
    const int x0 = pos0 & 63;
    const int yy = (pos0 >> 6) & 63, bb = pos0 >> 12;
    const int cy = min(max(yy, 3), 60);

    int cxr[4];
#pragma unroll
    for (int r = 0; r < 4; ++r)
        cxr[r] = min(max(x0 + quad * 4 + r, 3), 60) - x0 + 5;

    const int kc0 = min(max(x0 - 8 + lrow, 0), 63);
    const int kc1 = min(max(x0 + 8 + lrow, 0), 63);

    const bf16x8 qa = *(const bf16x8*)(QA + (size_t)(pos0 + lrow) * 256 + h * 32 + quad * 8);

    float* qp = qpes[w];
    const f32x4 zero = {0.f, 0.f, 0.f, 0.f};
#pragma unroll
    for (int Tn = 0; Tn < 4; ++Tn) {
        bf16x8 bp = *(const bf16x8*)(pebf + ((size_t)((h * 4 + Tn) * 64 + L)) * 8);
        f32x4 c = __builtin_amdgcn_mfma_f32_16x16x32_bf16(qa, bp, zero, 0, 0, 0);
#pragma unroll
        for (int r = 0; r < 4; ++r)
            qp[(quad * 4 + r) * 64 + Tn * 16 + lrow] = c[r];
    }
    __builtin_amdgcn_s_waitcnt(0xc07f);

    float lacc[4] = {0.f, 0.f, 0.f, 0.f};
    f32x4 o0 = zero, o1 = zero;
    unsigned short* pw = ps[w];
    int rowpos = bb * 4096 + (cy - 3) * 64;

    // preload dy=0 frags
    const size_t koff = h * 32 + quad * 8;
    const size_t voff0 = (size_t)(h * 32 + lrow) * 16384 + x0 - 8 + quad * 8;
    const size_t voff1 = (size_t)(h * 32 + 16 + lrow) * 16384 + x0 - 8 + quad * 8;
    bf16x8 bk0 = *(const bf16x8*)(Kd + (size_t)(rowpos + kc0) * 256 + koff);
    bf16x8 bk1 = *(const bf16x8*)(Kd + (size_t)(rowpos + kc1) * 256 + koff);
    bf16x8 bv0 = *(const bf16x8*)(Vt + voff0 + rowpos);
    bf16x8 bv1 = *(const bf16x8*)(Vt + voff1 + rowpos);

    for (int dy = 0; dy < 7; ++dy) {
        const int rnext = rowpos + 64;
        bf16x8 nk0, nk1, nv0, nv1;
        if (dy < 6) {                      // issue dy+1 loads (in flight)
            nk0 = *(const bf16x8*)(Kd + (size_t)(rnext + kc0) * 256 + koff);
            nk1 = *(const bf16x8*)(Kd + (size_t)(rnext + kc1) * 256 + koff);
            nv0 = *(const bf16x8*)(Vt + voff0 + rnext);
            nv1 = *(const bf16x8*)(Vt + voff1 + rnext);
        }
        f32x4 sc0 = __builtin_amdgcn_mfma_f32_16x16x32_bf16(qa, bk0, zero, 0, 0, 0);
        f32x4 sc1 = __builtin_amdgcn_mfma_f32_16x16x32_bf16(qa, bk1, zero, 0, 0, 0);
        const int dy7 = dy * 7;
#pragma unroll
        for (int r = 0; r < 4; ++r) {
            const int i = quad * 4 + r;
            {
                int dx3 = lrow - cxr[r];
                float qpe = qp[i * 64 + dy7 + min(max(dx3, 0), 6)];
                float e = exp2f(sc0[r] + qpe);
                float p = ((unsigned)dx3 <= 6u) ? e : 0.f;
                lacc[r] += p;
                pw[i * 40 + lrow] = bfbits(p);
            }
            {
                int dx3 = 16 + lrow - cxr[r];
                float qpe = qp[i * 64 + dy7 + min(max(dx3, 0), 6)];
                float e = exp2f(sc1[r] + qpe);
                float p = ((unsigned)dx3 <= 6u) ? e : 0.f;
                lacc[r] += p;
                pw[i * 40 + 16 + lrow] = bfbits(p);
            }
        }
        __builtin_amdgcn_s_waitcnt(0xc07f);
        const bf16x8 pa = *(const bf16x8*)(pw + lrow * 40 + quad * 8);
        o0 = __builtin_amdgcn_mfma_f32_16x16x32_bf16(pa, bv0, o0, 0, 0, 0);
        o1 = __builtin_amdgcn_mfma_f32_16x16x32_bf16(pa, bv1, o1, 0, 0, 0);
        bk0 = nk0; bk1 = nk1; bv0 = nv0; bv1 = nv1;
        rowpos = rnext;
    }

#pragma unroll
    for (int r = 0; r < 4; ++r) {
        float v = lacc[r];
        v += dpp_mov<0xB1>(v);
        v += dpp_mov<0x4E>(v);
        v += swz<0x101F>(v);
        v += swz<0x201F>(v);
        const float inv = 1.f / (v + 1e-8f);
        const int row = pos0 + quad * 4 + r;
        QA[(size_t)row * 256 + h * 32 + lrow]      = bfbits(o0[r] * inv);
        QA[(size_t)row * 256 + h * 32 + 16 + lrow] = bfbits(o1[r] * inv);
    }
}

// ---------------------------------------------------------------------------
// Kernel 3: output projection A(bf16) @ Wo -> out f32. 32-row tiles, grid
// 512; async gll staging (t<128), double-buffered.
// ---------------------------------------------------------------------------
__global__ __launch_bounds__(256, 4) void oproj_mfma(
    const unsigned short* __restrict__ A,
    const __hip_bfloat16* __restrict__ Wofrag,
    float* __restrict__ out)
{
    __shared__ __align__(16) short As[2][32 * 32];
    const int t = threadIdx.x;
    const int rowbase = blockIdx.x * 32;
    const int L = t & 63;
    const int wave = t >> 6;
    const int quad = L >> 4, lrow = L & 15;
    const int T = wave >> 1;
    const int ngb = (wave & 1) * 4;

    f32x4 acc[2][4];
#pragma unroll
    for (int i = 0; i < 2; ++i)
#pragma unroll
        for (int j = 0; j < 4; ++j) acc[i][j] = (f32x4){0.f, 0.f, 0.f, 0.f};

    const unsigned short* asrc = A + (size_t)(rowbase + (t >> 2)) * CD + (t & 3) * 8;
    short* d0 = &As[0][t * 8];
    short* d1 = &As[1][t * 8];

    if (t < 128) async16(d0, asrc);
    __syncthreads();

#pragma unroll
    for (int s = 0; s < 8; ++s) {
        if (s < 7 && t < 128) async16((s & 1) ? d0 : d1, asrc + (s + 1) * 32);
        bf16x8 bfr[4];
#pragma unroll
        for (int j = 0; j < 4; ++j)
            bfr[j] = *(const bf16x8*)(Wofrag +
                      ((size_t)((T * 8 + s) * 8 + ngb + j) * 64 + L) * 8);
        const short* Ab = As[s & 1];
#pragma unroll
        for (int i = 0; i < 2; ++i) {
            bf16x8 af = *(const bf16x8*)(Ab + (i * 16 + lrow) * 32 + quad * 8);
#pragma unroll
            for (int j = 0; j < 4; ++j)
                acc[i][j] = __builtin_amdgcn_mfma_f32_16x16x32_bf16(af, bfr[j], acc[i][j], 0, 0, 0);
        }
        __syncthreads();
    }

#pragma unroll
    for (int i = 0; i < 2; ++i)
#pragma unroll
        for (int r = 0; r < 4; ++r) {
            int row = rowbase + i * 16 + quad * 4 + r;
#pragma unroll
            for (int j = 0; j < 4; ++j) {
                int c = wave * 64 + j * 16 + lrow;
                out[(size_t)row * CD + c] = acc[i][j][r];
            }
        }
}

// ---------------------------------------------------------------------------
// Memory plan (ws ~256 MiB; we use ~25 MB):
//   ws[ 0,  8MB): QA bf16 (Q+pe_q -> in-place attn output A)
//   ws[ 8, 16MB): Kd bf16 (QSCALE-folded; tail absorbs Vt underflow reads)
//   ws[16, 24MB): Vt bf16 transposed [ch][16384]; 4KB pad after
//   ws[24MB+4KB, +544KB): Wfrag 384KB | pebf 32KB | Wofrag 128KB
// ---------------------------------------------------------------------------
extern "C" void kernel_launch(void* const* d_in, const int* in_sizes, int n_in,
                              void* d_out, int out_size, void* d_ws, size_t ws_size,
                              hipStream_t stream)
{
    const float* x  = (const float*)d_in[0];
    const float* Wq = (const float*)d_in[1];
    const float* Wk = (const float*)d_in[2];
    const float* Wv = (const float*)d_in[3];
    const float* Wo = (const float*)d_in[4];
    const float* pe = (const float*)d_in[5];
    float* out = (float*)d_out;

    char* ws = (char*)d_ws;
    unsigned short* QA = (unsigned short*)ws;
    unsigned short* Kd = (unsigned short*)(ws + (8u << 20));
    unsigned short* Vt = (unsigned short*)(ws + (16u << 20));
    char* fr = ws + (24u << 20) + 4096;
    __hip_bfloat16* Wfrag  = (__hip_bfloat16*)fr;
    __hip_bfloat16* pebf   = (__hip_bfloat16*)(fr + (384u << 10));
    __hip_bfloat16* Wofrag = (__hip_bfloat16*)(fr + (416u << 10));

    convert_kernel<<<136, 256, 0, stream>>>(Wq, Wk, Wv, Wo, pe, Wfrag, pebf, Wofrag);
    qkv_mfma<<<dim3(256, 3), 256, 0, stream>>>(x, Wfrag, pe, QA, Kd, Vt);
    attn_mfma<<<2048, 256, 0, stream>>>(QA, Kd, Vt, pebf);
    oproj_mfma<<<512, 256, 0, stream>>>(QA, Wofrag, out);
}